// Round 7
// baseline (940.913 us; speedup 1.0000x reference)
//
#include <hip/hip_runtime.h>
#include <hip/hip_bf16.h>

#define BN_EPS 1e-5f

using short8 = __attribute__((ext_vector_type(8))) short;
using f32x4  = __attribute__((ext_vector_type(4))) float;

// 32-bit packed histogram: cnt in [31:25], fixed-point ew-sum (2^-18) in [24:0].
// 8-way replicated per-XCD table (layout r*N + c). R3/R5 verified correct.
#define FIX_SCALE 262144.0f
#define FIX_MASK  0x01ffffffu
#define CNT_ONE   (1u << 25)

// Node-feature buffers are GROUP-MAJOR: channel c of node m lives at
// ushort index ((c>>4)*Mp + m)*16 + (c&15). Each 16-channel group is a
// contiguous 3.2MB region -> fits one XCD's 4MB L2 for the prop gathers.

static __device__ __forceinline__ unsigned short f2bf(float f) {
  unsigned int u = __float_as_uint(f);
  unsigned int r = (u + 0x7fffu + ((u >> 16) & 1u)) >> 16;
  return (unsigned short)r;
}

// ------------------------------------------------- weight cast
// B2 (GEMM1 weights) fragment-ordered: B2[k>>5][n][k&31]. BT2 (GEMM2) n-major.

static __global__ void cast_weights(const float* __restrict__ W1, const float* __restrict__ Wres,
                                    const float* __restrict__ W2,
                                    unsigned short* __restrict__ B2,
                                    unsigned short* __restrict__ BT2) {
  int i = blockIdx.x * blockDim.x + threadIdx.x;
  if (i < 256 * 256) {
    int n = i >> 8, k = i & 255;
    float v = (n < 128) ? W1[k * 128 + n] : Wres[k * 128 + (n - 128)];
    B2[(k >> 5) * 8192 + n * 32 + (k & 31)] = f2bf(v);
  } else if (i < 256 * 256 + 128 * 128) {
    int j = i - 256 * 256;
    int n = j >> 7, k = j & 127;
    BT2[j] = f2bf(W2[k * 128 + n]);
  }
}

// ---------------------------------------------------------------- hist (standalone)
static __global__ __launch_bounds__(256)
void hist_kernel(const int* __restrict__ col, const float* __restrict__ ew,
                 unsigned int* __restrict__ packed,
                 unsigned short* __restrict__ rank, int E, int N) {
  unsigned int xcc;
  asm volatile("s_getreg_b32 %0, hwreg(HW_REG_XCC_ID)" : "=s"(xcc));
  xcc &= 7u;
  unsigned int* mytab = packed + (size_t)xcc * N;
  int base = blockIdx.x * (256 * 4) + threadIdx.x;
#pragma unroll
  for (int j = 0; j < 4; ++j) {
    int e = base + j * 256;
    if (e < E) {
      int c = col[e];
      unsigned int fx = (unsigned int)(ew[e] * FIX_SCALE + 0.5f);
      unsigned int old = __hip_atomic_fetch_add(&mytab[c], CNT_ONE | fx,
                                                __ATOMIC_RELAXED,
                                                __HIP_MEMORY_SCOPE_WORKGROUP);
      rank[e] = (unsigned short)(((old >> 25) & 0x1fffu) | (xcc << 13));
    }
  }
}

// ---------------------------------------------------------------- GEMM1 (standalone)
// A-only LDS (double-buffered), B fragments from fragment-ordered B2, prefetched
// one k-step ahead. Epilogue writes GROUP-MAJOR C.

static __global__ __launch_bounds__(256)
void gemm1_kernel(const float* __restrict__ A, const unsigned short* __restrict__ B2,
                  unsigned short* __restrict__ C0, unsigned short* __restrict__ C1,
                  int M, int Mp) {
  __shared__ unsigned short As[2 * 64 * 40];

  int t = threadIdx.x;
  int wv = t >> 6, lane = t & 63;
  int quad = lane >> 4, l15 = lane & 15;
  int m0 = blockIdx.x * 64;

  f32x4 acc[4][4];
#pragma unroll
  for (int i = 0; i < 4; ++i)
#pragma unroll
    for (int j = 0; j < 4; ++j) acc[i][j] = (f32x4){0.f, 0.f, 0.f, 0.f};

  int ar = t >> 2;
  int ac = (t & 3) * 8;
  bool avalid = (m0 + ar) < M;
  const float* Arow = A + (size_t)(m0 + ar) * 256 + ac;
  const unsigned short* Bfrag = B2 + (wv * 64 + l15) * 32 + quad * 8;

  float4 a0 = make_float4(0.f, 0.f, 0.f, 0.f), a1 = a0;
  if (avalid) {
    a0 = *(const float4*)(Arow + 0);
    a1 = *(const float4*)(Arow + 4);
  }
  {
    short8 av;
    av[0] = (short)f2bf(a0.x); av[1] = (short)f2bf(a0.y);
    av[2] = (short)f2bf(a0.z); av[3] = (short)f2bf(a0.w);
    av[4] = (short)f2bf(a1.x); av[5] = (short)f2bf(a1.y);
    av[6] = (short)f2bf(a1.z); av[7] = (short)f2bf(a1.w);
    *(short8*)&As[ar * 40 + ac] = av;
  }
  short8 bc[4];
#pragma unroll
  for (int nt = 0; nt < 4; ++nt)
    bc[nt] = *(const short8*)(Bfrag + nt * 512);
  __syncthreads();

#pragma unroll 2
  for (int s = 0; s < 8; ++s) {
    int cur = (s & 1) ? 2560 : 0;

    short8 bn[4];
    if (s < 7) {
#pragma unroll
      for (int nt = 0; nt < 4; ++nt)
        bn[nt] = *(const short8*)(Bfrag + (s + 1) * 8192 + nt * 512);
      if (avalid) {
        a0 = *(const float4*)(Arow + (s + 1) * 32);
        a1 = *(const float4*)(Arow + (s + 1) * 32 + 4);
      }
    }

    short8 af[4];
#pragma unroll
    for (int mt = 0; mt < 4; ++mt)
      af[mt] = *(const short8*)&As[cur + (mt * 16 + l15) * 40 + quad * 8];
#pragma unroll
    for (int mt = 0; mt < 4; ++mt)
#pragma unroll
      for (int nt = 0; nt < 4; ++nt)
        acc[mt][nt] = __builtin_amdgcn_mfma_f32_16x16x32_bf16(af[mt], bc[nt], acc[mt][nt], 0, 0, 0);

    if (s < 7) {
      short8 av;
      av[0] = (short)f2bf(a0.x); av[1] = (short)f2bf(a0.y);
      av[2] = (short)f2bf(a0.z); av[3] = (short)f2bf(a0.w);
      av[4] = (short)f2bf(a1.x); av[5] = (short)f2bf(a1.y);
      av[6] = (short)f2bf(a1.z); av[7] = (short)f2bf(a1.w);
      *(short8*)&As[(cur ^ 2560) + ar * 40 + ac] = av;
#pragma unroll
      for (int nt = 0; nt < 4; ++nt) bc[nt] = bn[nt];
    }
    __syncthreads();
  }

  int nbase = wv * 64;
#pragma unroll
  for (int mt = 0; mt < 4; ++mt) {
#pragma unroll
    for (int nt = 0; nt < 4; ++nt) {
      int n = nbase + nt * 16 + l15;
      int nn = (n < 128) ? n : n - 128;
      unsigned short* Cd = (n < 128) ? C0 : C1;
      size_t grp = (size_t)(nn >> 4) * Mp;
#pragma unroll
      for (int reg = 0; reg < 4; ++reg) {
        size_t m = (size_t)(m0 + mt * 16 + quad * 4 + reg);
        Cd[(grp + m) * 16 + (nn & 15)] = f2bf(acc[mt][nt][reg]);
      }
    }
  }
}

// ---------------------------------------------------------------- scan over 8N virtual nodes

#define SCAN_B 256
#define SCAN_I 16
static __global__ void scanA(const unsigned int* __restrict__ packed,
                             float* __restrict__ dis, int* __restrict__ cnt,
                             int* __restrict__ startV, int* __restrict__ blkSum, int N) {
  __shared__ int sh[SCAN_B];
  int t = threadIdx.x;
  int vbase = blockIdx.x * (SCAN_B * SCAN_I) + t * SCAN_I;
  int v[SCAN_I];
  int tot = 0;
#pragma unroll
  for (int g = 0; g < 2; ++g) {
    int c = (vbase >> 3) + g;
    int csum = 0;
    if (c < N) {
      unsigned int usum = 0;
#pragma unroll
      for (int r = 0; r < 8; ++r) {
        unsigned int pv = packed[(size_t)r * N + c];
        int cr = (int)(pv >> 25);
        v[g * 8 + r] = cr;
        csum += cr;
        usum += (pv & FIX_MASK);
      }
      cnt[c] = csum;
      dis[c] = rsqrtf(1.0f + (float)usum * (1.0f / FIX_SCALE));
    } else {
#pragma unroll
      for (int r = 0; r < 8; ++r) v[g * 8 + r] = 0;
    }
    tot += csum;
  }
  sh[t] = tot;
  __syncthreads();
  int self = tot;
  for (int off = 1; off < SCAN_B; off <<= 1) {
    int add = (t >= off) ? sh[t - off] : 0;
    __syncthreads();
    sh[t] += add;
    __syncthreads();
  }
  int excl = sh[t] - self;
  if (t == SCAN_B - 1) blkSum[blockIdx.x] = sh[t];
  int run = excl;
#pragma unroll
  for (int j = 0; j < SCAN_I; ++j) {
    if (vbase + j < 8 * N) startV[vbase + j] = run;
    run += v[j];
  }
}

static __global__ void scanB(const int* __restrict__ blkSum, int* __restrict__ blkOff, int nb) {
  __shared__ int sh[256];
  int t = threadIdx.x;
  int v = (t < nb) ? blkSum[t] : 0;
  sh[t] = v;
  __syncthreads();
  for (int off = 1; off < 256; off <<= 1) {
    int add = (t >= off) ? sh[t - off] : 0;
    __syncthreads();
    sh[t] += add;
    __syncthreads();
  }
  if (t < nb) blkOff[t] = sh[t] - v;
}

static __global__ void scanC(int* startV, const int* __restrict__ blkOff, int NV) {
  int i = blockIdx.x * blockDim.x + threadIdx.x;
  if (i < NV) startV[i] += blkOff[i / (SCAN_B * SCAN_I)];
}

static __global__ void place_kernel(const int* __restrict__ row, const int* __restrict__ col,
                                    const float* __restrict__ ew, const float* __restrict__ dis,
                                    const int* __restrict__ startV,
                                    const unsigned short* __restrict__ rank,
                                    long long* __restrict__ edges, int E) {
  int e = blockIdx.x * blockDim.x + threadIdx.x;
  if (e < E) {
    int r = row[e], c = col[e];
    unsigned int rk = rank[e];
    int pos = startV[c * 8 + (rk >> 13)] + (int)(rk & 0x1fffu);
    float nrm = dis[r] * ew[e];
    long long v = ((long long)__float_as_int(nrm) << 32) | (unsigned int)r;
    __builtin_nontemporal_store(v, &edges[pos]);
  }
}

// ---------------------------------------------------------------- GEMM2 (group-major A & C)

static __global__ __launch_bounds__(256)
void gemm2_mfma(const unsigned short* __restrict__ A, const unsigned short* __restrict__ BT,
                unsigned short* __restrict__ C, int Mp) {
  __shared__ unsigned short As[128 * 40];
  __shared__ unsigned short Bs[128 * 40];
  int t = threadIdx.x;
  int wv = t >> 6, lane = t & 63;
  int quad = lane >> 4, l15 = lane & 15;
  int m0 = blockIdx.x * 128;

  f32x4 acc[4][4];
#pragma unroll
  for (int i = 0; i < 4; ++i)
#pragma unroll
    for (int j = 0; j < 4; ++j) acc[i][j] = (f32x4){0.f, 0.f, 0.f, 0.f};

  int sr = t >> 1, sc = (t & 1) * 16;

  for (int k0 = 0; k0 < 128; k0 += 32) {
    // A row (m0+sr), channels [k0+sc, k0+sc+16) = one full group-row, 32B contiguous
    const unsigned short* Ar = A + ((size_t)((k0 + sc) >> 4) * Mp + (m0 + sr)) * 16;
    short8 a0 = *(const short8*)(Ar);
    short8 a1 = *(const short8*)(Ar + 8);
    *(short8*)&As[sr * 40 + sc]     = a0;
    *(short8*)&As[sr * 40 + sc + 8] = a1;
    short8 b0 = *(const short8*)(BT + (size_t)sr * 128 + k0 + sc);
    short8 b1 = *(const short8*)(BT + (size_t)sr * 128 + k0 + sc + 8);
    *(short8*)&Bs[sr * 40 + sc]     = b0;
    *(short8*)&Bs[sr * 40 + sc + 8] = b1;
    __syncthreads();

    int mb = (wv >> 1) * 64, nb = (wv & 1) * 64;
    short8 af[4], bf[4];
#pragma unroll
    for (int mt = 0; mt < 4; ++mt)
      af[mt] = *(const short8*)&As[(mb + mt * 16 + l15) * 40 + quad * 8];
#pragma unroll
    for (int nt = 0; nt < 4; ++nt)
      bf[nt] = *(const short8*)&Bs[(nb + nt * 16 + l15) * 40 + quad * 8];
#pragma unroll
    for (int mt = 0; mt < 4; ++mt)
#pragma unroll
      for (int nt = 0; nt < 4; ++nt)
        acc[mt][nt] = __builtin_amdgcn_mfma_f32_16x16x32_bf16(af[mt], bf[nt], acc[mt][nt], 0, 0, 0);
    __syncthreads();
  }

  int mb = (wv >> 1) * 64, nb = (wv & 1) * 64;
#pragma unroll
  for (int mt = 0; mt < 4; ++mt)
#pragma unroll
    for (int nt = 0; nt < 4; ++nt) {
      int n = nb + nt * 16 + l15;
      size_t grp = (size_t)(n >> 4) * Mp;
#pragma unroll
      for (int reg = 0; reg < 4; ++reg) {
        size_t m = (size_t)(m0 + mb + mt * 16 + quad * 4 + reg);
        C[(grp + m) * 16 + (n & 15)] = f2bf(acc[mt][nt][reg]);
      }
    }
}

// ---------------------------------------------------------------- channel-split propagation
// Group g = blockIdx.x & 7 (round-robin -> pinned to XCD g; correctness does not
// depend on the mapping). Wave = 8 edges x 8 lanes; lane w = lane&7 holds one
// bf16x2 word (2 channels) of the 16-channel group row (32B, L2-resident).
// Edge records loaded per-lane (broadcast in 8-lane subgroups, no shuffles),
// software-pipelined one iteration ahead of the gather.

static __global__ __launch_bounds__(256)
void prop1_split(const unsigned int* __restrict__ Hg,
                 const int* __restrict__ startV, const int* __restrict__ cnt,
                 const long long* __restrict__ edges,
                 const float* __restrict__ dis,
                 const float* __restrict__ bvec,
                 const float* __restrict__ gam, const float* __restrict__ bet,
                 const float* __restrict__ mean, const float* __restrict__ var,
                 unsigned int* __restrict__ Og, int N, int Mp) {
  int g = blockIdx.x & 7;
  int base = (blockIdx.x >> 3) * 16;
  int wv = threadIdx.x >> 6, lane = threadIdx.x & 63;
  int sub = lane >> 3, w = lane & 7;
  const unsigned int* H = Hg + (size_t)g * Mp * 8;
  unsigned int* O = Og + (size_t)g * Mp * 8;
  int c0 = g * 16 + w * 2;
  float s0 = gam[c0] * rsqrtf(var[c0] + BN_EPS);
  float s1 = gam[c0 + 1] * rsqrtf(var[c0 + 1] + BN_EPS);
  float mn0 = mean[c0], mn1 = mean[c0 + 1];
  float bt0 = bet[c0], bt1 = bet[c0 + 1];
  float bb0 = bvec[c0], bb1 = bvec[c0 + 1];

#pragma unroll
  for (int i = 0; i < 4; ++i) {
    int dst = base + wv * 4 + i;
    if (dst >= N) break;
    float d = dis[dst];
    float a0 = 0.f, a1 = 0.f;
    if (sub == 0) {
      unsigned int u = H[(size_t)dst * 8 + w];
      a0 = d * __uint_as_float(u << 16);
      a1 = d * __uint_as_float(u & 0xffff0000u);
    }
    int s = startV[(size_t)dst * 8], n = cnt[dst];
    int k = sub;
    long long ev = (k < n) ? edges[s + k] : 0;
    while (k < n) {
      int kn = k + 8;
      long long evn = (kn < n) ? edges[s + kn] : 0;
      int idx = (int)(unsigned int)(ev & 0xffffffffLL);
      float wt = __int_as_float((int)(ev >> 32));
      unsigned int u = H[(size_t)idx * 8 + w];
      a0 = fmaf(wt, __uint_as_float(u << 16), a0);
      a1 = fmaf(wt, __uint_as_float(u & 0xffff0000u), a1);
      ev = evn; k = kn;
    }
    // reduce across the 8 sub-waves (lane w preserved)
    a0 += __shfl_xor(a0, 8, 64);  a1 += __shfl_xor(a1, 8, 64);
    a0 += __shfl_xor(a0, 16, 64); a1 += __shfl_xor(a1, 16, 64);
    a0 += __shfl_xor(a0, 32, 64); a1 += __shfl_xor(a1, 32, 64);
    if (sub == 0) {
      float x0 = a0 * d + bb0;
      float x1 = a1 * d + bb1;
      x0 = fmaxf((x0 - mn0) * s0 + bt0, 0.f);
      x1 = fmaxf((x1 - mn1) * s1 + bt1, 0.f);
      O[(size_t)dst * 8 + w] = (unsigned int)f2bf(x0) | ((unsigned int)f2bf(x1) << 16);
    }
  }
}

// prop2: adds res (group-major), BN2+relu, partial W3 dot -> Hpart[g][dst]
static __global__ __launch_bounds__(256)
void prop2_split(const unsigned int* __restrict__ Hg,
                 const int* __restrict__ startV, const int* __restrict__ cnt,
                 const long long* __restrict__ edges,
                 const float* __restrict__ dis,
                 const float* __restrict__ bvec,
                 const float* __restrict__ gam, const float* __restrict__ bet,
                 const float* __restrict__ mean, const float* __restrict__ var,
                 const unsigned int* __restrict__ Resg, const float* __restrict__ W3,
                 float* __restrict__ Hpart, int N, int Mp) {
  int g = blockIdx.x & 7;
  int base = (blockIdx.x >> 3) * 16;
  int wv = threadIdx.x >> 6, lane = threadIdx.x & 63;
  int sub = lane >> 3, w = lane & 7;
  const unsigned int* H = Hg + (size_t)g * Mp * 8;
  const unsigned int* R = Resg + (size_t)g * Mp * 8;
  int c0 = g * 16 + w * 2;
  float s0 = gam[c0] * rsqrtf(var[c0] + BN_EPS);
  float s1 = gam[c0 + 1] * rsqrtf(var[c0 + 1] + BN_EPS);
  float mn0 = mean[c0], mn1 = mean[c0 + 1];
  float bt0 = bet[c0], bt1 = bet[c0 + 1];
  float bb0 = bvec[c0], bb1 = bvec[c0 + 1];
  float w30 = W3[c0], w31 = W3[c0 + 1];

#pragma unroll
  for (int i = 0; i < 4; ++i) {
    int dst = base + wv * 4 + i;
    if (dst >= N) break;
    float d = dis[dst];
    float a0 = 0.f, a1 = 0.f;
    if (sub == 0) {
      unsigned int u = H[(size_t)dst * 8 + w];
      a0 = d * __uint_as_float(u << 16);
      a1 = d * __uint_as_float(u & 0xffff0000u);
    }
    int s = startV[(size_t)dst * 8], n = cnt[dst];
    int k = sub;
    long long ev = (k < n) ? edges[s + k] : 0;
    while (k < n) {
      int kn = k + 8;
      long long evn = (kn < n) ? edges[s + kn] : 0;
      int idx = (int)(unsigned int)(ev & 0xffffffffLL);
      float wt = __int_as_float((int)(ev >> 32));
      unsigned int u = H[(size_t)idx * 8 + w];
      a0 = fmaf(wt, __uint_as_float(u << 16), a0);
      a1 = fmaf(wt, __uint_as_float(u & 0xffff0000u), a1);
      ev = evn; k = kn;
    }
    a0 += __shfl_xor(a0, 8, 64);  a1 += __shfl_xor(a1, 8, 64);
    a0 += __shfl_xor(a0, 16, 64); a1 += __shfl_xor(a1, 16, 64);
    a0 += __shfl_xor(a0, 32, 64); a1 += __shfl_xor(a1, 32, 64);
    float v = 0.f;
    if (sub == 0) {
      unsigned int ru = R[(size_t)dst * 8 + w];
      float x0 = a0 * d + bb0 + __uint_as_float(ru << 16);
      float x1 = a1 * d + bb1 + __uint_as_float(ru & 0xffff0000u);
      x0 = fmaxf((x0 - mn0) * s0 + bt0, 0.f);
      x1 = fmaxf((x1 - mn1) * s1 + bt1, 0.f);
      v = x0 * w30 + x1 * w31;
    }
    v += __shfl_down(v, 4, 64);
    v += __shfl_down(v, 2, 64);
    v += __shfl_down(v, 1, 64);
    if (lane == 0) Hpart[(size_t)g * Mp + dst] = v;
  }
}

static __global__ void reduce_h3(const float* __restrict__ Hpart, float* __restrict__ h3,
                                 int N, int Mp) {
  int i = blockIdx.x * blockDim.x + threadIdx.x;
  if (i < N) {
    float v = 0.f;
#pragma unroll
    for (int g = 0; g < 8; ++g) v += Hpart[(size_t)g * Mp + i];
    h3[i] = v;
  }
}

// ---------------------------------------------------------------- final 1-wide propagation

static __global__ void prop3_kernel(const float* __restrict__ h3,
                                    const int* __restrict__ start8, const int* __restrict__ cnt,
                                    const long long* __restrict__ edges,
                                    const float* __restrict__ dis, const float* __restrict__ b3,
                                    float* __restrict__ out, int N) {
  int i = blockIdx.x * blockDim.x + threadIdx.x;
  if (i >= N) return;
  float d = dis[i];
  float acc = d * h3[i];
  int s = start8[(size_t)i * 8], n = cnt[i];
  for (int k = 0; k < n; ++k) {
    long long ev = edges[s + k];
    int src = (int)(unsigned int)(ev & 0xffffffffLL);
    float wt = __int_as_float((int)(ev >> 32));
    acc = fmaf(wt, h3[src], acc);
  }
  out[i] = acc * d + b3[0];
}

// ---------------------------------------------------------------- launch

extern "C" void kernel_launch(void* const* d_in, const int* in_sizes, int n_in,
                              void* d_out, int out_size, void* d_ws, size_t ws_size,
                              hipStream_t stream) {
  const float* x    = (const float*)d_in[0];
  const int*   ei   = (const int*)d_in[1];
  const float* ew   = (const float*)d_in[2];
  const float* W1   = (const float*)d_in[3];
  const float* b1   = (const float*)d_in[4];
  const float* W2   = (const float*)d_in[5];
  const float* b2   = (const float*)d_in[6];
  const float* W3   = (const float*)d_in[7];
  const float* b3   = (const float*)d_in[8];
  const float* Wres = (const float*)d_in[9];
  const float* g1   = (const float*)d_in[10];
  const float* be1  = (const float*)d_in[11];
  const float* m1   = (const float*)d_in[12];
  const float* v1   = (const float*)d_in[13];
  const float* g2   = (const float*)d_in[14];
  const float* be2  = (const float*)d_in[15];
  const float* m2   = (const float*)d_in[16];
  const float* v2   = (const float*)d_in[17];

  int Hh = in_sizes[4];            // 128
  int V  = in_sizes[3] / Hh;       // 256
  int N  = in_sizes[0] / V;        // 100000
  int E  = in_sizes[2];            // 1600000
  const int* row = ei;
  const int* col = ei + E;

  int Mp = ((N + 127) / 128) * 128;

  char* p = (char*)d_ws;
  auto alloc = [&](size_t bytes) -> char* {
    char* r = p;
    p += (bytes + 255) & ~(size_t)255;
    return r;
  };
  unsigned int* packed = (unsigned int*)alloc((size_t)N * 8 * 4);   // 8 per-XCD replicas
  float* dis    = (float*)alloc((size_t)N * 4);
  int*   cnt    = (int*)  alloc((size_t)N * 4);
  int*   startV = (int*)  alloc((size_t)N * 8 * 4);                 // 8N virtual nodes
  int*   blkSum = (int*)  alloc(256 * 4);
  int*   blkOff = (int*)  alloc(256 * 4);
  unsigned short* rank = (unsigned short*)alloc((size_t)E * 2);
  long long* edges = (long long*)alloc((size_t)E * 8);
  float* h3     = (float*)alloc((size_t)N * 4);
  float* Hpart  = (float*)alloc((size_t)Mp * 8 * 4);
  unsigned short* B2  = (unsigned short*)alloc((size_t)256 * 256 * 2);
  unsigned short* BT2 = (unsigned short*)alloc((size_t)128 * 128 * 2);
  unsigned short* bufG  = (unsigned short*)alloc((size_t)Mp * 128 * 2);  // group-major
  unsigned short* bufH1 = (unsigned short*)alloc((size_t)Mp * 128 * 2);  // group-major
  unsigned short* bufRes = (unsigned short*)alloc((size_t)Mp * 128 * 2); // group-major
  (void)ws_size; (void)n_in; (void)out_size;

  int TB = 256;
  hipMemsetAsync(packed, 0, (size_t)N * 8 * 4, stream);
  cast_weights<<<(256 * 256 + 128 * 128 + TB - 1) / TB, TB, 0, stream>>>(W1, Wres, W2, B2, BT2);

  int hB = (E + TB * 4 - 1) / (TB * 4);
  hist_kernel<<<hB, TB, 0, stream>>>(col, ew, packed, rank, E, N);
  gemm1_kernel<<<Mp / 64, TB, 0, stream>>>(x, B2, bufG, bufRes, N, Mp);

  int NV = 8 * N;
  int nb = (NV + SCAN_B * SCAN_I - 1) / (SCAN_B * SCAN_I);
  scanA<<<nb, SCAN_B, 0, stream>>>(packed, dis, cnt, startV, blkSum, N);
  scanB<<<1, 256, 0, stream>>>(blkSum, blkOff, nb);
  scanC<<<(NV + TB - 1) / TB, TB, 0, stream>>>(startV, blkOff, NV);
  place_kernel<<<(E + TB - 1) / TB, TB, 0, stream>>>(row, col, ew, dis, startV,
                                                     rank, edges, E);

  // channel-split props: 8 groups x (N/16 nodes per block)
  int pB = 8 * ((N + 15) / 16);
  prop1_split<<<pB, TB, 0, stream>>>((const unsigned int*)bufG, startV, cnt,
                                     edges, dis, b1, g1, be1, m1, v1,
                                     (unsigned int*)bufH1, N, Mp);

  gemm2_mfma<<<Mp / 128, 256, 0, stream>>>(bufH1, BT2, bufG, Mp);

  prop2_split<<<pB, TB, 0, stream>>>((const unsigned int*)bufG, startV, cnt,
                                     edges, dis, b2, g2, be2, m2, v2,
                                     (const unsigned int*)bufRes, W3, Hpart, N, Mp);
  reduce_h3<<<(N + TB - 1) / TB, TB, 0, stream>>>(Hpart, h3, N, Mp);

  prop3_kernel<<<(N + TB - 1) / TB, TB, 0, stream>>>(h3, startV, cnt, edges,
                                                     dis, b3, (float*)d_out, N);
}

// Round 11
// 484.928 us; speedup vs baseline: 1.9403x; 1.9403x over previous
//
#include <hip/hip_runtime.h>
#include <hip/hip_bf16.h>

#define BN_EPS 1e-5f

using short8 = __attribute__((ext_vector_type(8))) short;
using f32x4  = __attribute__((ext_vector_type(4))) float;

// 32-bit packed histogram: cnt in [31:25], fixed-point ew-sum (2^-18) in [24:0].
// 8-way replicated per-XCD table (layout r*N + c), workgroup-scope fetch-add.
#define FIX_SCALE 262144.0f
#define FIX_MASK  0x01ffffffu
#define CNT_ONE   (1u << 25)

static __device__ __forceinline__ unsigned short f2bf(float f) {
  unsigned int u = __float_as_uint(f);
  unsigned int r = (u + 0x7fffu + ((u >> 16) & 1u)) >> 16;
  return (unsigned short)r;
}

// ------------------------------------------------- weight cast
// B2 (GEMM1 weights) fragment-ordered: B2[k>>5][n][k&31]. BT2 (GEMM2) n-major.

static __global__ void cast_weights(const float* __restrict__ W1, const float* __restrict__ Wres,
                                    const float* __restrict__ W2,
                                    unsigned short* __restrict__ B2,
                                    unsigned short* __restrict__ BT2) {
  int i = blockIdx.x * blockDim.x + threadIdx.x;
  if (i < 256 * 256) {
    int n = i >> 8, k = i & 255;
    float v = (n < 128) ? W1[k * 128 + n] : Wres[k * 128 + (n - 128)];
    B2[(k >> 5) * 8192 + n * 32 + (k & 31)] = f2bf(v);
  } else if (i < 256 * 256 + 128 * 128) {
    int j = i - 256 * 256;
    int n = j >> 7, k = j & 127;
    BT2[j] = f2bf(W2[k * 128 + n]);
  }
}

// ---------------------------------------------------------------- fused GEMM1 + hist
// (R5 fusion recovered: atomic-pipe hist overlaps MFMA gemm. +R6 B-prefetch.)
// GEMM blocks [0,gB): A-only LDS dbuf, one barrier/k-step, B frags direct from
//   L2-resident B2, prefetched one k-step ahead.
// hist blocks [gB,..): per-XCD replica, workgroup-scope returning fetch-add.
//   rank[e] = per-(c,xcd) rank (13 bits) | xcd (3 bits).

static __global__ __launch_bounds__(256)
void fused_gemm1_hist(const float* __restrict__ A, const unsigned short* __restrict__ B2,
                      unsigned short* __restrict__ C0, unsigned short* __restrict__ C1, int M,
                      const int* __restrict__ col, const float* __restrict__ ew,
                      unsigned int* __restrict__ packed,
                      unsigned short* __restrict__ rank, int E, int gB, int N) {
  __shared__ unsigned short As[2 * 64 * 40];   // 10 KB double-buffered A tile

  int b = blockIdx.x;
  if (b >= gB) {
    unsigned int xcc;
    asm volatile("s_getreg_b32 %0, hwreg(HW_REG_XCC_ID)" : "=s"(xcc));
    xcc &= 7u;
    unsigned int* mytab = packed + (size_t)xcc * N;
    int base = (b - gB) * (256 * 4) + threadIdx.x;
#pragma unroll
    for (int j = 0; j < 4; ++j) {
      int e = base + j * 256;
      if (e < E) {
        int c = col[e];
        unsigned int fx = (unsigned int)(ew[e] * FIX_SCALE + 0.5f);
        unsigned int old = __hip_atomic_fetch_add(&mytab[c], CNT_ONE | fx,
                                                  __ATOMIC_RELAXED,
                                                  __HIP_MEMORY_SCOPE_WORKGROUP);
        rank[e] = (unsigned short)(((old >> 25) & 0x1fffu) | (xcc << 13));
      }
    }
    return;
  }

  // ---------------- gemm role
  int t = threadIdx.x;
  int wv = t >> 6, lane = t & 63;
  int quad = lane >> 4, l15 = lane & 15;
  int m0 = b * 64;

  f32x4 acc[4][4];
#pragma unroll
  for (int i = 0; i < 4; ++i)
#pragma unroll
    for (int j = 0; j < 4; ++j) acc[i][j] = (f32x4){0.f, 0.f, 0.f, 0.f};

  int ar = t >> 2;
  int ac = (t & 3) * 8;
  bool avalid = (m0 + ar) < M;
  const float* Arow = A + (size_t)(m0 + ar) * 256 + ac;
  const unsigned short* Bfrag = B2 + (wv * 64 + l15) * 32 + quad * 8;

  float4 a0 = make_float4(0.f, 0.f, 0.f, 0.f), a1 = a0;
  if (avalid) {
    a0 = *(const float4*)(Arow + 0);
    a1 = *(const float4*)(Arow + 4);
  }
  {
    short8 av;
    av[0] = (short)f2bf(a0.x); av[1] = (short)f2bf(a0.y);
    av[2] = (short)f2bf(a0.z); av[3] = (short)f2bf(a0.w);
    av[4] = (short)f2bf(a1.x); av[5] = (short)f2bf(a1.y);
    av[6] = (short)f2bf(a1.z); av[7] = (short)f2bf(a1.w);
    *(short8*)&As[ar * 40 + ac] = av;
  }
  short8 bc[4];
#pragma unroll
  for (int nt = 0; nt < 4; ++nt)
    bc[nt] = *(const short8*)(Bfrag + nt * 512);
  __syncthreads();

#pragma unroll 2
  for (int s = 0; s < 8; ++s) {
    int cur = (s & 1) ? 2560 : 0;

    short8 bn[4];
    if (s < 7) {
#pragma unroll
      for (int nt = 0; nt < 4; ++nt)
        bn[nt] = *(const short8*)(Bfrag + (s + 1) * 8192 + nt * 512);
      if (avalid) {
        a0 = *(const float4*)(Arow + (s + 1) * 32);
        a1 = *(const float4*)(Arow + (s + 1) * 32 + 4);
      }
    }

    short8 af[4];
#pragma unroll
    for (int mt = 0; mt < 4; ++mt)
      af[mt] = *(const short8*)&As[cur + (mt * 16 + l15) * 40 + quad * 8];
#pragma unroll
    for (int mt = 0; mt < 4; ++mt)
#pragma unroll
      for (int nt = 0; nt < 4; ++nt)
        acc[mt][nt] = __builtin_amdgcn_mfma_f32_16x16x32_bf16(af[mt], bc[nt], acc[mt][nt], 0, 0, 0);

    if (s < 7) {
      short8 av;
      av[0] = (short)f2bf(a0.x); av[1] = (short)f2bf(a0.y);
      av[2] = (short)f2bf(a0.z); av[3] = (short)f2bf(a0.w);
      av[4] = (short)f2bf(a1.x); av[5] = (short)f2bf(a1.y);
      av[6] = (short)f2bf(a1.z); av[7] = (short)f2bf(a1.w);
      *(short8*)&As[(cur ^ 2560) + ar * 40 + ac] = av;
#pragma unroll
      for (int nt = 0; nt < 4; ++nt) bc[nt] = bn[nt];
    }
    __syncthreads();
  }

  int nbase = wv * 64;
#pragma unroll
  for (int mt = 0; mt < 4; ++mt) {
#pragma unroll
    for (int nt = 0; nt < 4; ++nt) {
      int n = nbase + nt * 16 + l15;
#pragma unroll
      for (int reg = 0; reg < 4; ++reg) {
        size_t m = (size_t)(m0 + mt * 16 + quad * 4 + reg);
        if (nbase < 128) C0[m * 128 + n] = f2bf(acc[mt][nt][reg]);
        else             C1[m * 128 + (n - 128)] = f2bf(acc[mt][nt][reg]);
      }
    }
  }
}

// ---------------------------------------------------------------- scan over 8N virtual nodes

#define SCAN_B 256
#define SCAN_I 16
static __global__ void scanA(const unsigned int* __restrict__ packed,
                             float* __restrict__ dis, int* __restrict__ cnt,
                             int* __restrict__ startV, int* __restrict__ blkSum, int N) {
  __shared__ int sh[SCAN_B];
  int t = threadIdx.x;
  int vbase = blockIdx.x * (SCAN_B * SCAN_I) + t * SCAN_I;
  int v[SCAN_I];
  int tot = 0;
#pragma unroll
  for (int g = 0; g < 2; ++g) {
    int c = (vbase >> 3) + g;
    int csum = 0;
    if (c < N) {
      unsigned int usum = 0;
#pragma unroll
      for (int r = 0; r < 8; ++r) {
        unsigned int pv = packed[(size_t)r * N + c];
        int cr = (int)(pv >> 25);
        v[g * 8 + r] = cr;
        csum += cr;
        usum += (pv & FIX_MASK);
      }
      cnt[c] = csum;
      dis[c] = rsqrtf(1.0f + (float)usum * (1.0f / FIX_SCALE));
    } else {
#pragma unroll
      for (int r = 0; r < 8; ++r) v[g * 8 + r] = 0;
    }
    tot += csum;
  }
  sh[t] = tot;
  __syncthreads();
  int self = tot;
  for (int off = 1; off < SCAN_B; off <<= 1) {
    int add = (t >= off) ? sh[t - off] : 0;
    __syncthreads();
    sh[t] += add;
    __syncthreads();
  }
  int excl = sh[t] - self;
  if (t == SCAN_B - 1) blkSum[blockIdx.x] = sh[t];
  int run = excl;
#pragma unroll
  for (int j = 0; j < SCAN_I; ++j) {
    if (vbase + j < 8 * N) startV[vbase + j] = run;
    run += v[j];
  }
}

static __global__ void scanB(const int* __restrict__ blkSum, int* __restrict__ blkOff, int nb) {
  __shared__ int sh[256];
  int t = threadIdx.x;
  int v = (t < nb) ? blkSum[t] : 0;
  sh[t] = v;
  __syncthreads();
  for (int off = 1; off < 256; off <<= 1) {
    int add = (t >= off) ? sh[t - off] : 0;
    __syncthreads();
    sh[t] += add;
    __syncthreads();
  }
  if (t < nb) blkOff[t] = sh[t] - v;
}

static __global__ void scanC(int* startV, const int* __restrict__ blkOff, int NV) {
  int i = blockIdx.x * blockDim.x + threadIdx.x;
  if (i < NV) startV[i] += blkOff[i / (SCAN_B * SCAN_I)];
}

static __global__ void place_kernel(const int* __restrict__ row, const int* __restrict__ col,
                                    const float* __restrict__ ew, const float* __restrict__ dis,
                                    const int* __restrict__ startV,
                                    const unsigned short* __restrict__ rank,
                                    long long* __restrict__ edges, int E) {
  int e = blockIdx.x * blockDim.x + threadIdx.x;
  if (e < E) {
    int r = row[e], c = col[e];
    unsigned int rk = rank[e];
    int pos = startV[c * 8 + (rk >> 13)] + (int)(rk & 0x1fffu);
    float nrm = dis[r] * ew[e];
    long long v = ((long long)__float_as_int(nrm) << 32) | (unsigned int)r;
    __builtin_nontemporal_store(v, &edges[pos]);
  }
}

// ---------------------------------------------------------------- GEMM2 (row-major, LDS-staged)

static __global__ __launch_bounds__(256)
void gemm2_mfma(const unsigned short* __restrict__ A, const unsigned short* __restrict__ BT,
                unsigned short* __restrict__ C) {
  __shared__ unsigned short As[128 * 40];
  __shared__ unsigned short Bs[128 * 40];
  int t = threadIdx.x;
  int wv = t >> 6, lane = t & 63;
  int quad = lane >> 4, l15 = lane & 15;
  int m0 = blockIdx.x * 128;

  f32x4 acc[4][4];
#pragma unroll
  for (int i = 0; i < 4; ++i)
#pragma unroll
    for (int j = 0; j < 4; ++j) acc[i][j] = (f32x4){0.f, 0.f, 0.f, 0.f};

  int sr = t >> 1, sc = (t & 1) * 16;

  for (int k0 = 0; k0 < 128; k0 += 32) {
    short8 a0 = *(const short8*)(A + (size_t)(m0 + sr) * 128 + k0 + sc);
    short8 a1 = *(const short8*)(A + (size_t)(m0 + sr) * 128 + k0 + sc + 8);
    *(short8*)&As[sr * 40 + sc]     = a0;
    *(short8*)&As[sr * 40 + sc + 8] = a1;
    short8 b0 = *(const short8*)(BT + (size_t)sr * 128 + k0 + sc);
    short8 b1 = *(const short8*)(BT + (size_t)sr * 128 + k0 + sc + 8);
    *(short8*)&Bs[sr * 40 + sc]     = b0;
    *(short8*)&Bs[sr * 40 + sc + 8] = b1;
    __syncthreads();

    int mb = (wv >> 1) * 64, nb = (wv & 1) * 64;
    short8 af[4], bf[4];
#pragma unroll
    for (int mt = 0; mt < 4; ++mt)
      af[mt] = *(const short8*)&As[(mb + mt * 16 + l15) * 40 + quad * 8];
#pragma unroll
    for (int nt = 0; nt < 4; ++nt)
      bf[nt] = *(const short8*)&Bs[(nb + nt * 16 + l15) * 40 + quad * 8];
#pragma unroll
    for (int mt = 0; mt < 4; ++mt)
#pragma unroll
      for (int nt = 0; nt < 4; ++nt)
        acc[mt][nt] = __builtin_amdgcn_mfma_f32_16x16x32_bf16(af[mt], bf[nt], acc[mt][nt], 0, 0, 0);
    __syncthreads();
  }

  int mb = (wv >> 1) * 64, nb = (wv & 1) * 64;
#pragma unroll
  for (int mt = 0; mt < 4; ++mt)
#pragma unroll
    for (int nt = 0; nt < 4; ++nt) {
      int n = nb + nt * 16 + l15;
#pragma unroll
      for (int reg = 0; reg < 4; ++reg) {
        size_t m = (size_t)(m0 + mb + mt * 16 + quad * 4 + reg);
        C[m * 128 + n] = f2bf(acc[mt][nt][reg]);
      }
    }
}

// ---------------------------------------------------------------- propagation core (R6 row-major)
// One wave per destination node; lane holds 2 channels. 8 coalesced 256B row
// gathers in flight per chunk — the MLP that R7's split destroyed.

#define PROP_GATHER_BODY                                                        \
  int c0 = lane * 2;                                                            \
  float d = dis[w];                                                             \
  float acc0, acc1;                                                             \
  {                                                                             \
    unsigned int u = Hsrc[(size_t)w * 64 + lane];                               \
    acc0 = d * __uint_as_float(u << 16);                                        \
    acc1 = d * __uint_as_float(u & 0xffff0000u);                                \
  }                                                                             \
  int s = start8[(size_t)w * 8], n = cnt[w];                                    \
  int k = 0;                                                                    \
  while (k < n) {                                                               \
    int chunk = min(n - k, 64);                                                 \
    int idx = 0;                                                                \
    float wt = 0.f;                                                             \
    if (lane < chunk) {                                                         \
      long long ev = edges[s + k + lane];                                       \
      idx = (int)(unsigned int)(ev & 0xffffffffLL);                             \
      wt  = __int_as_float((int)(ev >> 32));                                    \
    }                                                                           \
    for (int j = 0; j < chunk; j += 8) {                                        \
      int   i0 = __shfl(idx, j + 0, 64), i1 = __shfl(idx, j + 1, 64);           \
      int   i2 = __shfl(idx, j + 2, 64), i3 = __shfl(idx, j + 3, 64);           \
      int   i4 = __shfl(idx, j + 4, 64), i5 = __shfl(idx, j + 5, 64);           \
      int   i6 = __shfl(idx, j + 6, 64), i7 = __shfl(idx, j + 7, 64);           \
      float w0 = __shfl(wt, j + 0, 64), w1 = __shfl(wt, j + 1, 64);             \
      float w2 = __shfl(wt, j + 2, 64), w3 = __shfl(wt, j + 3, 64);             \
      float w4 = __shfl(wt, j + 4, 64), w5 = __shfl(wt, j + 5, 64);             \
      float w6 = __shfl(wt, j + 6, 64), w7 = __shfl(wt, j + 7, 64);             \
      unsigned int u0 = Hsrc[(size_t)i0 * 64 + lane];                           \
      unsigned int u1 = Hsrc[(size_t)i1 * 64 + lane];                           \
      unsigned int u2 = Hsrc[(size_t)i2 * 64 + lane];                           \
      unsigned int u3 = Hsrc[(size_t)i3 * 64 + lane];                           \
      unsigned int u4 = Hsrc[(size_t)i4 * 64 + lane];                           \
      unsigned int u5 = Hsrc[(size_t)i5 * 64 + lane];                           \
      unsigned int u6 = Hsrc[(size_t)i6 * 64 + lane];                           \
      unsigned int u7 = Hsrc[(size_t)i7 * 64 + lane];                           \
      acc0 = fmaf(w0, __uint_as_float(u0 << 16), acc0);                         \
      acc1 = fmaf(w0, __uint_as_float(u0 & 0xffff0000u), acc1);                 \
      acc0 = fmaf(w1, __uint_as_float(u1 << 16), acc0);                         \
      acc1 = fmaf(w1, __uint_as_float(u1 & 0xffff0000u), acc1);                 \
      acc0 = fmaf(w2, __uint_as_float(u2 << 16), acc0);                         \
      acc1 = fmaf(w2, __uint_as_float(u2 & 0xffff0000u), acc1);                 \
      acc0 = fmaf(w3, __uint_as_float(u3 << 16), acc0);                         \
      acc1 = fmaf(w3, __uint_as_float(u3 & 0xffff0000u), acc1);                 \
      acc0 = fmaf(w4, __uint_as_float(u4 << 16), acc0);                         \
      acc1 = fmaf(w4, __uint_as_float(u4 & 0xffff0000u), acc1);                 \
      acc0 = fmaf(w5, __uint_as_float(u5 << 16), acc0);                         \
      acc1 = fmaf(w5, __uint_as_float(u5 & 0xffff0000u), acc1);                 \
      acc0 = fmaf(w6, __uint_as_float(u6 << 16), acc0);                         \
      acc1 = fmaf(w6, __uint_as_float(u6 & 0xffff0000u), acc1);                 \
      acc0 = fmaf(w7, __uint_as_float(u7 << 16), acc0);                         \
      acc1 = fmaf(w7, __uint_as_float(u7 & 0xffff0000u), acc1);                 \
    }                                                                           \
    k += chunk;                                                                 \
  }                                                                             \
  acc0 *= d;                                                                    \
  acc1 *= d;

static __global__ __launch_bounds__(256)
void prop128_bf16out(const unsigned int* __restrict__ Hsrc,
                     const int* __restrict__ start8, const int* __restrict__ cnt,
                     const long long* __restrict__ edges,
                     const float* __restrict__ dis,
                     const float* __restrict__ bvec,
                     const float* __restrict__ g, const float* __restrict__ be,
                     const float* __restrict__ mean, const float* __restrict__ var,
                     unsigned int* __restrict__ Outb, int N) {
  int w = (int)((blockIdx.x * blockDim.x + threadIdx.x) >> 6);
  int lane = threadIdx.x & 63;
  if (w >= N) return;
  PROP_GATHER_BODY
  float x0 = acc0 + bvec[c0];
  float x1 = acc1 + bvec[c0 + 1];
  float s0 = g[c0] * rsqrtf(var[c0] + BN_EPS);
  float s1 = g[c0 + 1] * rsqrtf(var[c0 + 1] + BN_EPS);
  x0 = fmaxf((x0 - mean[c0]) * s0 + be[c0], 0.f);
  x1 = fmaxf((x1 - mean[c0 + 1]) * s1 + be[c0 + 1], 0.f);
  unsigned int packed = (unsigned int)f2bf(x0) | ((unsigned int)f2bf(x1) << 16);
  Outb[(size_t)w * 64 + lane] = packed;
}

static __global__ __launch_bounds__(256)
void prop128_w3out(const unsigned int* __restrict__ Hsrc,
                   const int* __restrict__ start8, const int* __restrict__ cnt,
                   const long long* __restrict__ edges,
                   const float* __restrict__ dis,
                   const float* __restrict__ bvec,
                   const float* __restrict__ g, const float* __restrict__ be,
                   const float* __restrict__ mean, const float* __restrict__ var,
                   const unsigned int* __restrict__ resb, const float* __restrict__ W3,
                   float* __restrict__ h3, int N) {
  int w = (int)((blockIdx.x * blockDim.x + threadIdx.x) >> 6);
  int lane = threadIdx.x & 63;
  if (w >= N) return;
  PROP_GATHER_BODY
  unsigned int ru = resb[(size_t)w * 64 + lane];
  float x0 = acc0 + bvec[c0]     + __uint_as_float(ru << 16);
  float x1 = acc1 + bvec[c0 + 1] + __uint_as_float(ru & 0xffff0000u);
  float s0 = g[c0] * rsqrtf(var[c0] + BN_EPS);
  float s1 = g[c0 + 1] * rsqrtf(var[c0 + 1] + BN_EPS);
  x0 = fmaxf((x0 - mean[c0]) * s0 + be[c0], 0.f);
  x1 = fmaxf((x1 - mean[c0 + 1]) * s1 + be[c0 + 1], 0.f);
  float v = x0 * W3[c0] + x1 * W3[c0 + 1];
#pragma unroll
  for (int off = 32; off > 0; off >>= 1) v += __shfl_down(v, off, 64);
  if (lane == 0) h3[w] = v;
}

// ---------------------------------------------------------------- final 1-wide propagation
// 4 lanes per node: h3 is 400KB (L2-resident); parallelize the 17-avg-degree
// serial loop 4x and reduce with two shuffles.

static __global__ __launch_bounds__(256)
void prop3_kernel(const float* __restrict__ h3,
                  const int* __restrict__ start8, const int* __restrict__ cnt,
                  const long long* __restrict__ edges,
                  const float* __restrict__ dis, const float* __restrict__ b3,
                  float* __restrict__ out, int N) {
  int tid = blockIdx.x * blockDim.x + threadIdx.x;
  int i = tid >> 2;
  int sub = tid & 3;
  if (i >= N) return;
  float acc = 0.f;
  int s = start8[(size_t)i * 8], n = cnt[i];
  for (int k = sub; k < n; k += 4) {
    long long ev = edges[s + k];
    int src = (int)(unsigned int)(ev & 0xffffffffLL);
    float wt = __int_as_float((int)(ev >> 32));
    acc = fmaf(wt, h3[src], acc);
  }
  acc += __shfl_xor(acc, 1, 64);
  acc += __shfl_xor(acc, 2, 64);
  if (sub == 0) {
    float d = dis[i];
    out[i] = (acc + d * h3[i]) * d + b3[0];
  }
}

// ---------------------------------------------------------------- launch

extern "C" void kernel_launch(void* const* d_in, const int* in_sizes, int n_in,
                              void* d_out, int out_size, void* d_ws, size_t ws_size,
                              hipStream_t stream) {
  const float* x    = (const float*)d_in[0];
  const int*   ei   = (const int*)d_in[1];
  const float* ew   = (const float*)d_in[2];
  const float* W1   = (const float*)d_in[3];
  const float* b1   = (const float*)d_in[4];
  const float* W2   = (const float*)d_in[5];
  const float* b2   = (const float*)d_in[6];
  const float* W3   = (const float*)d_in[7];
  const float* b3   = (const float*)d_in[8];
  const float* Wres = (const float*)d_in[9];
  const float* g1   = (const float*)d_in[10];
  const float* be1  = (const float*)d_in[11];
  const float* m1   = (const float*)d_in[12];
  const float* v1   = (const float*)d_in[13];
  const float* g2   = (const float*)d_in[14];
  const float* be2  = (const float*)d_in[15];
  const float* m2   = (const float*)d_in[16];
  const float* v2   = (const float*)d_in[17];

  int Hh = in_sizes[4];            // 128
  int V  = in_sizes[3] / Hh;       // 256
  int N  = in_sizes[0] / V;        // 100000
  int E  = in_sizes[2];            // 1600000
  const int* row = ei;
  const int* col = ei + E;

  int Mp = ((N + 127) / 128) * 128;

  char* p = (char*)d_ws;
  auto alloc = [&](size_t bytes) -> char* {
    char* r = p;
    p += (bytes + 255) & ~(size_t)255;
    return r;
  };
  unsigned int* packed = (unsigned int*)alloc((size_t)N * 8 * 4);   // 8 per-XCD replicas
  float* dis    = (float*)alloc((size_t)N * 4);
  int*   cnt    = (int*)  alloc((size_t)N * 4);
  int*   startV = (int*)  alloc((size_t)N * 8 * 4);                 // 8N virtual nodes
  int*   blkSum = (int*)  alloc(256 * 4);
  int*   blkOff = (int*)  alloc(256 * 4);
  unsigned short* rank = (unsigned short*)alloc((size_t)E * 2);
  long long* edges = (long long*)alloc((size_t)E * 8);
  float* h3     = (float*)alloc((size_t)N * 4);
  unsigned short* B2  = (unsigned short*)alloc((size_t)256 * 256 * 2);
  unsigned short* BT2 = (unsigned short*)alloc((size_t)128 * 128 * 2);
  unsigned short* bufG  = (unsigned short*)alloc((size_t)Mp * 128 * 2);  // h0, then h1W2 (bf16)
  unsigned short* bufH1 = (unsigned short*)alloc((size_t)Mp * 128 * 2);  // h1 bf16
  unsigned short* bufRes = (unsigned short*)alloc((size_t)Mp * 128 * 2); // x@Wres bf16
  (void)ws_size; (void)n_in; (void)out_size;

  int TB = 256;
  hipMemsetAsync(packed, 0, (size_t)N * 8 * 4, stream);
  cast_weights<<<(256 * 256 + 128 * 128 + TB - 1) / TB, TB, 0, stream>>>(W1, Wres, W2, B2, BT2);

  // fused: GEMM1 (blocks [0,gB)) + hist (blocks [gB, gB+hB), 4 edges/thread)
  int gB = Mp / 64;
  int hB = (E + TB * 4 - 1) / (TB * 4);
  fused_gemm1_hist<<<gB + hB, TB, 0, stream>>>(x, B2, bufG, bufRes, N,
                                               col, ew, packed, rank, E, gB, N);

  int NV = 8 * N;
  int nb = (NV + SCAN_B * SCAN_I - 1) / (SCAN_B * SCAN_I);
  scanA<<<nb, SCAN_B, 0, stream>>>(packed, dis, cnt, startV, blkSum, N);
  scanB<<<1, 256, 0, stream>>>(blkSum, blkOff, nb);
  scanC<<<(NV + TB - 1) / TB, TB, 0, stream>>>(startV, blkOff, NV);
  place_kernel<<<(E + TB - 1) / TB, TB, 0, stream>>>(row, col, ew, dis, startV,
                                                     rank, edges, E);

  // prop1: h1 = relu(bn1(agg(h0) + b1)) -> bufH1 (bf16)
  int propBlocks = (int)(((size_t)N * 64 + TB - 1) / TB);
  prop128_bf16out<<<propBlocks, TB, 0, stream>>>((const unsigned int*)bufG, startV, cnt,
                                                 edges, dis, b1, g1, be1, m1, v1,
                                                 (unsigned int*)bufH1, N);

  // GEMM2: h1 @ W2 -> bufG (bf16, reused)
  gemm2_mfma<<<Mp / 128, 256, 0, stream>>>(bufH1, BT2, bufG);

  // prop2 + fused W3: h3 = relu(bn2(agg(h1W2) + b2 + res)) . W3
  prop128_w3out<<<propBlocks, TB, 0, stream>>>((const unsigned int*)bufG, startV, cnt,
                                               edges, dis, b2, g2, be2, m2, v2,
                                               (const unsigned int*)bufRes, W3, h3, N);

  // out = agg(h3) + b3 (4 lanes/node)
  prop3_kernel<<<(int)(((size_t)N * 4 + TB - 1) / TB), TB, 0, stream>>>(h3, startV, cnt, edges,
                                                                        dis, b3, (float*)d_out, N);
}

// Round 13
// 483.338 us; speedup vs baseline: 1.9467x; 1.0033x over previous
//
#include <hip/hip_runtime.h>
#include <hip/hip_bf16.h>

#define BN_EPS 1e-5f

using short8 = __attribute__((ext_vector_type(8))) short;
using f32x4  = __attribute__((ext_vector_type(4))) float;

// 32-bit packed histogram: cnt in [31:25], fixed-point ew-sum (2^-18) in [24:0].
// 8-way replicated per-XCD table (layout r*N + c), workgroup-scope fetch-add.
#define FIX_SCALE 262144.0f
#define FIX_MASK  0x01ffffffu
#define CNT_ONE   (1u << 25)

static __device__ __forceinline__ unsigned short f2bf(float f) {
  unsigned int u = __float_as_uint(f);
  unsigned int r = (u + 0x7fffu + ((u >> 16) & 1u)) >> 16;
  return (unsigned short)r;
}

// ------------------------------------------------- weight cast
// B2 (GEMM1 weights) fragment-ordered: B2[k>>5][n][k&31]. BT2 (GEMM2) n-major.

static __global__ void cast_weights(const float* __restrict__ W1, const float* __restrict__ Wres,
                                    const float* __restrict__ W2,
                                    unsigned short* __restrict__ B2,
                                    unsigned short* __restrict__ BT2) {
  int i = blockIdx.x * blockDim.x + threadIdx.x;
  if (i < 256 * 256) {
    int n = i >> 8, k = i & 255;
    float v = (n < 128) ? W1[k * 128 + n] : Wres[k * 128 + (n - 128)];
    B2[(k >> 5) * 8192 + n * 32 + (k & 31)] = f2bf(v);
  } else if (i < 256 * 256 + 128 * 128) {
    int j = i - 256 * 256;
    int n = j >> 7, k = j & 127;
    BT2[j] = f2bf(W2[k * 128 + n]);
  }
}

// ---------------------------------------------------------------- fused HIST + GEMM1
// HIST FIRST (blocks [0,hB), 8 edges/thread): with 96 VGPR the kernel gets
// ~5 blocks/CU = 1280 slots; hB=782 hist blocks + 498 gemm blocks are
// co-resident from t=0, so the atomic-latency hist waves overlap the
// MFMA/L3-latency gemm waves (R11 counters showed the old gemm-first layout
// ran the roles serially: dur ~= sum of standalone roles).
// GEMM blocks [hB,..): A-only LDS dbuf, one barrier/k-step, B frags direct
// from L2-resident B2, prefetched one k-step ahead.

static __global__ __launch_bounds__(256)
void fused_gemm1_hist(const float* __restrict__ A, const unsigned short* __restrict__ B2,
                      unsigned short* __restrict__ C0, unsigned short* __restrict__ C1, int M,
                      const int* __restrict__ col, const float* __restrict__ ew,
                      unsigned int* __restrict__ packed,
                      unsigned short* __restrict__ rank, int E, int hB, int N) {
  __shared__ unsigned short As[2 * 64 * 40];   // 10 KB double-buffered A tile

  int b = blockIdx.x;
  if (b < hB) {
    // ---------------- hist role: 8 independent returning atomics in flight/thread
    unsigned int xcc;
    asm volatile("s_getreg_b32 %0, hwreg(HW_REG_XCC_ID)" : "=s"(xcc));
    xcc &= 7u;
    unsigned int* mytab = packed + (size_t)xcc * N;
    int base = b * (256 * 8) + threadIdx.x;
#pragma unroll
    for (int j = 0; j < 8; ++j) {
      int e = base + j * 256;
      if (e < E) {
        int c = col[e];
        unsigned int fx = (unsigned int)(ew[e] * FIX_SCALE + 0.5f);
        unsigned int old = __hip_atomic_fetch_add(&mytab[c], CNT_ONE | fx,
                                                  __ATOMIC_RELAXED,
                                                  __HIP_MEMORY_SCOPE_WORKGROUP);
        rank[e] = (unsigned short)(((old >> 25) & 0x1fffu) | (xcc << 13));
      }
    }
    return;
  }

  // ---------------- gemm role
  int t = threadIdx.x;
  int wv = t >> 6, lane = t & 63;
  int quad = lane >> 4, l15 = lane & 15;
  int m0 = (b - hB) * 64;

  f32x4 acc[4][4];
#pragma unroll
  for (int i = 0; i < 4; ++i)
#pragma unroll
    for (int j = 0; j < 4; ++j) acc[i][j] = (f32x4){0.f, 0.f, 0.f, 0.f};

  int ar = t >> 2;
  int ac = (t & 3) * 8;
  bool avalid = (m0 + ar) < M;
  const float* Arow = A + (size_t)(m0 + ar) * 256 + ac;
  const unsigned short* Bfrag = B2 + (wv * 64 + l15) * 32 + quad * 8;

  float4 a0 = make_float4(0.f, 0.f, 0.f, 0.f), a1 = a0;
  if (avalid) {
    a0 = *(const float4*)(Arow + 0);
    a1 = *(const float4*)(Arow + 4);
  }
  {
    short8 av;
    av[0] = (short)f2bf(a0.x); av[1] = (short)f2bf(a0.y);
    av[2] = (short)f2bf(a0.z); av[3] = (short)f2bf(a0.w);
    av[4] = (short)f2bf(a1.x); av[5] = (short)f2bf(a1.y);
    av[6] = (short)f2bf(a1.z); av[7] = (short)f2bf(a1.w);
    *(short8*)&As[ar * 40 + ac] = av;
  }
  short8 bc[4];
#pragma unroll
  for (int nt = 0; nt < 4; ++nt)
    bc[nt] = *(const short8*)(Bfrag + nt * 512);
  __syncthreads();

#pragma unroll 2
  for (int s = 0; s < 8; ++s) {
    int cur = (s & 1) ? 2560 : 0;

    short8 bn[4];
    if (s < 7) {
#pragma unroll
      for (int nt = 0; nt < 4; ++nt)
        bn[nt] = *(const short8*)(Bfrag + (s + 1) * 8192 + nt * 512);
      if (avalid) {
        a0 = *(const float4*)(Arow + (s + 1) * 32);
        a1 = *(const float4*)(Arow + (s + 1) * 32 + 4);
      }
    }

    short8 af[4];
#pragma unroll
    for (int mt = 0; mt < 4; ++mt)
      af[mt] = *(const short8*)&As[cur + (mt * 16 + l15) * 40 + quad * 8];
#pragma unroll
    for (int mt = 0; mt < 4; ++mt)
#pragma unroll
      for (int nt = 0; nt < 4; ++nt)
        acc[mt][nt] = __builtin_amdgcn_mfma_f32_16x16x32_bf16(af[mt], bc[nt], acc[mt][nt], 0, 0, 0);

    if (s < 7) {
      short8 av;
      av[0] = (short)f2bf(a0.x); av[1] = (short)f2bf(a0.y);
      av[2] = (short)f2bf(a0.z); av[3] = (short)f2bf(a0.w);
      av[4] = (short)f2bf(a1.x); av[5] = (short)f2bf(a1.y);
      av[6] = (short)f2bf(a1.z); av[7] = (short)f2bf(a1.w);
      *(short8*)&As[(cur ^ 2560) + ar * 40 + ac] = av;
#pragma unroll
      for (int nt = 0; nt < 4; ++nt) bc[nt] = bn[nt];
    }
    __syncthreads();
  }

  int nbase = wv * 64;
#pragma unroll
  for (int mt = 0; mt < 4; ++mt) {
#pragma unroll
    for (int nt = 0; nt < 4; ++nt) {
      int n = nbase + nt * 16 + l15;
#pragma unroll
      for (int reg = 0; reg < 4; ++reg) {
        size_t m = (size_t)(m0 + mt * 16 + quad * 4 + reg);
        if (nbase < 128) C0[m * 128 + n] = f2bf(acc[mt][nt][reg]);
        else             C1[m * 128 + (n - 128)] = f2bf(acc[mt][nt][reg]);
      }
    }
  }
}

// ---------------------------------------------------------------- scan over 8N virtual nodes
// scanA writes BLOCK-LOCAL exclusive offsets into startV; the global base
// blkOff[v>>12] is added by consumers (place/props) — scanC eliminated.

#define SCAN_B 256
#define SCAN_I 16
static __global__ void scanA(const unsigned int* __restrict__ packed,
                             float* __restrict__ dis, int* __restrict__ cnt,
                             int* __restrict__ startV, int* __restrict__ blkSum, int N) {
  __shared__ int sh[SCAN_B];
  int t = threadIdx.x;
  int vbase = blockIdx.x * (SCAN_B * SCAN_I) + t * SCAN_I;
  int v[SCAN_I];
  int tot = 0;
#pragma unroll
  for (int g = 0; g < 2; ++g) {
    int c = (vbase >> 3) + g;
    int csum = 0;
    if (c < N) {
      unsigned int usum = 0;
#pragma unroll
      for (int r = 0; r < 8; ++r) {
        unsigned int pv = packed[(size_t)r * N + c];
        int cr = (int)(pv >> 25);
        v[g * 8 + r] = cr;
        csum += cr;
        usum += (pv & FIX_MASK);
      }
      cnt[c] = csum;
      dis[c] = rsqrtf(1.0f + (float)usum * (1.0f / FIX_SCALE));
    } else {
#pragma unroll
      for (int r = 0; r < 8; ++r) v[g * 8 + r] = 0;
    }
    tot += csum;
  }
  sh[t] = tot;
  __syncthreads();
  int self = tot;
  for (int off = 1; off < SCAN_B; off <<= 1) {
    int add = (t >= off) ? sh[t - off] : 0;
    __syncthreads();
    sh[t] += add;
    __syncthreads();
  }
  int excl = sh[t] - self;
  if (t == SCAN_B - 1) blkSum[blockIdx.x] = sh[t];
  int run = excl;
#pragma unroll
  for (int j = 0; j < SCAN_I; ++j) {
    if (vbase + j < 8 * N) startV[vbase + j] = run;
    run += v[j];
  }
}

static __global__ void scanB(const int* __restrict__ blkSum, int* __restrict__ blkOff, int nb) {
  __shared__ int sh[256];
  int t = threadIdx.x;
  int v = (t < nb) ? blkSum[t] : 0;
  sh[t] = v;
  __syncthreads();
  for (int off = 1; off < 256; off <<= 1) {
    int add = (t >= off) ? sh[t - off] : 0;
    __syncthreads();
    sh[t] += add;
    __syncthreads();
  }
  if (t < nb) blkOff[t] = sh[t] - v;
}

static __global__ void place_kernel(const int* __restrict__ row, const int* __restrict__ col,
                                    const float* __restrict__ ew, const float* __restrict__ dis,
                                    const int* __restrict__ startV, const int* __restrict__ blkOff,
                                    const unsigned short* __restrict__ rank,
                                    long long* __restrict__ edges, int E) {
  int e = blockIdx.x * blockDim.x + threadIdx.x;
  if (e < E) {
    int r = row[e], c = col[e];
    unsigned int rk = rank[e];
    int vv = c * 8 + (int)(rk >> 13);
    int pos = startV[vv] + blkOff[vv >> 12] + (int)(rk & 0x1fffu);
    float nrm = dis[r] * ew[e];
    long long v = ((long long)__float_as_int(nrm) << 32) | (unsigned int)r;
    __builtin_nontemporal_store(v, &edges[pos]);
  }
}

// ---------------------------------------------------------------- GEMM2 (row-major, LDS-staged)

static __global__ __launch_bounds__(256)
void gemm2_mfma(const unsigned short* __restrict__ A, const unsigned short* __restrict__ BT,
                unsigned short* __restrict__ C) {
  __shared__ unsigned short As[128 * 40];
  __shared__ unsigned short Bs[128 * 40];
  int t = threadIdx.x;
  int wv = t >> 6, lane = t & 63;
  int quad = lane >> 4, l15 = lane & 15;
  int m0 = blockIdx.x * 128;

  f32x4 acc[4][4];
#pragma unroll
  for (int i = 0; i < 4; ++i)
#pragma unroll
    for (int j = 0; j < 4; ++j) acc[i][j] = (f32x4){0.f, 0.f, 0.f, 0.f};

  int sr = t >> 1, sc = (t & 1) * 16;

  for (int k0 = 0; k0 < 128; k0 += 32) {
    short8 a0 = *(const short8*)(A + (size_t)(m0 + sr) * 128 + k0 + sc);
    short8 a1 = *(const short8*)(A + (size_t)(m0 + sr) * 128 + k0 + sc + 8);
    *(short8*)&As[sr * 40 + sc]     = a0;
    *(short8*)&As[sr * 40 + sc + 8] = a1;
    short8 b0 = *(const short8*)(BT + (size_t)sr * 128 + k0 + sc);
    short8 b1 = *(const short8*)(BT + (size_t)sr * 128 + k0 + sc + 8);
    *(short8*)&Bs[sr * 40 + sc]     = b0;
    *(short8*)&Bs[sr * 40 + sc + 8] = b1;
    __syncthreads();

    int mb = (wv >> 1) * 64, nb = (wv & 1) * 64;
    short8 af[4], bf[4];
#pragma unroll
    for (int mt = 0; mt < 4; ++mt)
      af[mt] = *(const short8*)&As[(mb + mt * 16 + l15) * 40 + quad * 8];
#pragma unroll
    for (int nt = 0; nt < 4; ++nt)
      bf[nt] = *(const short8*)&Bs[(nb + nt * 16 + l15) * 40 + quad * 8];
#pragma unroll
    for (int mt = 0; mt < 4; ++mt)
#pragma unroll
      for (int nt = 0; nt < 4; ++nt)
        acc[mt][nt] = __builtin_amdgcn_mfma_f32_16x16x32_bf16(af[mt], bf[nt], acc[mt][nt], 0, 0, 0);
    __syncthreads();
  }

  int mb = (wv >> 1) * 64, nb = (wv & 1) * 64;
#pragma unroll
  for (int mt = 0; mt < 4; ++mt)
#pragma unroll
    for (int nt = 0; nt < 4; ++nt) {
      int n = nb + nt * 16 + l15;
#pragma unroll
      for (int reg = 0; reg < 4; ++reg) {
        size_t m = (size_t)(m0 + mb + mt * 16 + quad * 4 + reg);
        C[m * 128 + n] = f2bf(acc[mt][nt][reg]);
      }
    }
}

// ---------------------------------------------------------------- propagation core (row-major)
// One wave per destination node; lane holds 2 channels. 8 coalesced 256B row
// gathers in flight per chunk. start = startV[w*8] + blkOff[w>>9] (scanC folded).

#define PROP_GATHER_BODY                                                        \
  int c0 = lane * 2;                                                            \
  float d = dis[w];                                                             \
  float acc0, acc1;                                                             \
  {                                                                             \
    unsigned int u = Hsrc[(size_t)w * 64 + lane];                               \
    acc0 = d * __uint_as_float(u << 16);                                        \
    acc1 = d * __uint_as_float(u & 0xffff0000u);                                \
  }                                                                             \
  int s = start8[(size_t)w * 8] + blkOff[w >> 9], n = cnt[w];                   \
  int k = 0;                                                                    \
  while (k < n) {                                                               \
    int chunk = min(n - k, 64);                                                 \
    int idx = 0;                                                                \
    float wt = 0.f;                                                             \
    if (lane < chunk) {                                                         \
      long long ev = edges[s + k + lane];                                       \
      idx = (int)(unsigned int)(ev & 0xffffffffLL);                             \
      wt  = __int_as_float((int)(ev >> 32));                                    \
    }                                                                           \
    for (int j = 0; j < chunk; j += 8) {                                        \
      int   i0 = __shfl(idx, j + 0, 64), i1 = __shfl(idx, j + 1, 64);           \
      int   i2 = __shfl(idx, j + 2, 64), i3 = __shfl(idx, j + 3, 64);           \
      int   i4 = __shfl(idx, j + 4, 64), i5 = __shfl(idx, j + 5, 64);           \
      int   i6 = __shfl(idx, j + 6, 64), i7 = __shfl(idx, j + 7, 64);           \
      float w0 = __shfl(wt, j + 0, 64), w1 = __shfl(wt, j + 1, 64);             \
      float w2 = __shfl(wt, j + 2, 64), w3 = __shfl(wt, j + 3, 64);             \
      float w4 = __shfl(wt, j + 4, 64), w5 = __shfl(wt, j + 5, 64);             \
      float w6 = __shfl(wt, j + 6, 64), w7 = __shfl(wt, j + 7, 64);             \
      unsigned int u0 = Hsrc[(size_t)i0 * 64 + lane];                           \
      unsigned int u1 = Hsrc[(size_t)i1 * 64 + lane];                           \
      unsigned int u2 = Hsrc[(size_t)i2 * 64 + lane];                           \
      unsigned int u3 = Hsrc[(size_t)i3 * 64 + lane];                           \
      unsigned int u4 = Hsrc[(size_t)i4 * 64 + lane];                           \
      unsigned int u5 = Hsrc[(size_t)i5 * 64 + lane];                           \
      unsigned int u6 = Hsrc[(size_t)i6 * 64 + lane];                           \
      unsigned int u7 = Hsrc[(size_t)i7 * 64 + lane];                           \
      acc0 = fmaf(w0, __uint_as_float(u0 << 16), acc0);                         \
      acc1 = fmaf(w0, __uint_as_float(u0 & 0xffff0000u), acc1);                 \
      acc0 = fmaf(w1, __uint_as_float(u1 << 16), acc0);                         \
      acc1 = fmaf(w1, __uint_as_float(u1 & 0xffff0000u), acc1);                 \
      acc0 = fmaf(w2, __uint_as_float(u2 << 16), acc0);                         \
      acc1 = fmaf(w2, __uint_as_float(u2 & 0xffff0000u), acc1);                 \
      acc0 = fmaf(w3, __uint_as_float(u3 << 16), acc0);                         \
      acc1 = fmaf(w3, __uint_as_float(u3 & 0xffff0000u), acc1);                 \
      acc0 = fmaf(w4, __uint_as_float(u4 << 16), acc0);                         \
      acc1 = fmaf(w4, __uint_as_float(u4 & 0xffff0000u), acc1);                 \
      acc0 = fmaf(w5, __uint_as_float(u5 << 16), acc0);                         \
      acc1 = fmaf(w5, __uint_as_float(u5 & 0xffff0000u), acc1);                 \
      acc0 = fmaf(w6, __uint_as_float(u6 << 16), acc0);                         \
      acc1 = fmaf(w6, __uint_as_float(u6 & 0xffff0000u), acc1);                 \
      acc0 = fmaf(w7, __uint_as_float(u7 << 16), acc0);                         \
      acc1 = fmaf(w7, __uint_as_float(u7 & 0xffff0000u), acc1);                 \
    }                                                                           \
    k += chunk;                                                                 \
  }                                                                             \
  acc0 *= d;                                                                    \
  acc1 *= d;

static __global__ __launch_bounds__(256)
void prop128_bf16out(const unsigned int* __restrict__ Hsrc,
                     const int* __restrict__ start8, const int* __restrict__ blkOff,
                     const int* __restrict__ cnt,
                     const long long* __restrict__ edges,
                     const float* __restrict__ dis,
                     const float* __restrict__ bvec,
                     const float* __restrict__ g, const float* __restrict__ be,
                     const float* __restrict__ mean, const float* __restrict__ var,
                     unsigned int* __restrict__ Outb, int N) {
  int w = (int)((blockIdx.x * blockDim.x + threadIdx.x) >> 6);
  int lane = threadIdx.x & 63;
  if (w >= N) return;
  PROP_GATHER_BODY
  float x0 = acc0 + bvec[c0];
  float x1 = acc1 + bvec[c0 + 1];
  float s0 = g[c0] * rsqrtf(var[c0] + BN_EPS);
  float s1 = g[c0 + 1] * rsqrtf(var[c0 + 1] + BN_EPS);
  x0 = fmaxf((x0 - mean[c0]) * s0 + be[c0], 0.f);
  x1 = fmaxf((x1 - mean[c0 + 1]) * s1 + be[c0 + 1], 0.f);
  unsigned int packed = (unsigned int)f2bf(x0) | ((unsigned int)f2bf(x1) << 16);
  Outb[(size_t)w * 64 + lane] = packed;
}

static __global__ __launch_bounds__(256)
void prop128_w3out(const unsigned int* __restrict__ Hsrc,
                   const int* __restrict__ start8, const int* __restrict__ blkOff,
                   const int* __restrict__ cnt,
                   const long long* __restrict__ edges,
                   const float* __restrict__ dis,
                   const float* __restrict__ bvec,
                   const float* __restrict__ g, const float* __restrict__ be,
                   const float* __restrict__ mean, const float* __restrict__ var,
                   const unsigned int* __restrict__ resb, const float* __restrict__ W3,
                   float* __restrict__ h3, int N) {
  int w = (int)((blockIdx.x * blockDim.x + threadIdx.x) >> 6);
  int lane = threadIdx.x & 63;
  if (w >= N) return;
  PROP_GATHER_BODY
  unsigned int ru = resb[(size_t)w * 64 + lane];
  float x0 = acc0 + bvec[c0]     + __uint_as_float(ru << 16);
  float x1 = acc1 + bvec[c0 + 1] + __uint_as_float(ru & 0xffff0000u);
  float s0 = g[c0] * rsqrtf(var[c0] + BN_EPS);
  float s1 = g[c0 + 1] * rsqrtf(var[c0 + 1] + BN_EPS);
  x0 = fmaxf((x0 - mean[c0]) * s0 + be[c0], 0.f);
  x1 = fmaxf((x1 - mean[c0 + 1]) * s1 + be[c0 + 1], 0.f);
  float v = x0 * W3[c0] + x1 * W3[c0 + 1];
#pragma unroll
  for (int off = 32; off > 0; off >>= 1) v += __shfl_down(v, off, 64);
  if (lane == 0) h3[w] = v;
}

// ---------------------------------------------------------------- final 1-wide propagation
// 4 lanes per node over L2-resident h3; 2-shuffle reduce.

static __global__ __launch_bounds__(256)
void prop3_kernel(const float* __restrict__ h3,
                  const int* __restrict__ start8, const int* __restrict__ blkOff,
                  const int* __restrict__ cnt,
                  const long long* __restrict__ edges,
                  const float* __restrict__ dis, const float* __restrict__ b3,
                  float* __restrict__ out, int N) {
  int tid = blockIdx.x * blockDim.x + threadIdx.x;
  int i = tid >> 2;
  int sub = tid & 3;
  if (i >= N) return;
  float acc = 0.f;
  int s = start8[(size_t)i * 8] + blkOff[i >> 9], n = cnt[i];
  for (int k = sub; k < n; k += 4) {
    long long ev = edges[s + k];
    int src = (int)(unsigned int)(ev & 0xffffffffLL);
    float wt = __int_as_float((int)(ev >> 32));
    acc = fmaf(wt, h3[src], acc);
  }
  acc += __shfl_xor(acc, 1, 64);
  acc += __shfl_xor(acc, 2, 64);
  if (sub == 0) {
    float d = dis[i];
    out[i] = (acc + d * h3[i]) * d + b3[0];
  }
}

// ---------------------------------------------------------------- launch

extern "C" void kernel_launch(void* const* d_in, const int* in_sizes, int n_in,
                              void* d_out, int out_size, void* d_ws, size_t ws_size,
                              hipStream_t stream) {
  const float* x    = (const float*)d_in[0];
  const int*   ei   = (const int*)d_in[1];
  const float* ew   = (const float*)d_in[2];
  const float* W1   = (const float*)d_in[3];
  const float* b1   = (const float*)d_in[4];
  const float* W2   = (const float*)d_in[5];
  const float* b2   = (const float*)d_in[6];
  const float* W3   = (const float*)d_in[7];
  const float* b3   = (const float*)d_in[8];
  const float* Wres = (const float*)d_in[9];
  const float* g1   = (const float*)d_in[10];
  const float* be1  = (const float*)d_in[11];
  const float* m1   = (const float*)d_in[12];
  const float* v1   = (const float*)d_in[13];
  const float* g2   = (const float*)d_in[14];
  const float* be2  = (const float*)d_in[15];
  const float* m2   = (const float*)d_in[16];
  const float* v2   = (const float*)d_in[17];

  int Hh = in_sizes[4];            // 128
  int V  = in_sizes[3] / Hh;       // 256
  int N  = in_sizes[0] / V;        // 100000
  int E  = in_sizes[2];            // 1600000
  const int* row = ei;
  const int* col = ei + E;

  int Mp = ((N + 127) / 128) * 128;

  char* p = (char*)d_ws;
  auto alloc = [&](size_t bytes) -> char* {
    char* r = p;
    p += (bytes + 255) & ~(size_t)255;
    return r;
  };
  unsigned int* packed = (unsigned int*)alloc((size_t)N * 8 * 4);   // 8 per-XCD replicas
  float* dis    = (float*)alloc((size_t)N * 4);
  int*   cnt    = (int*)  alloc((size_t)N * 4);
  int*   startV = (int*)  alloc((size_t)N * 8 * 4);                 // 8N virtual nodes (block-local)
  int*   blkSum = (int*)  alloc(256 * 4);
  int*   blkOff = (int*)  alloc(256 * 4);
  unsigned short* rank = (unsigned short*)alloc((size_t)E * 2);
  long long* edges = (long long*)alloc((size_t)E * 8);
  float* h3     = (float*)alloc((size_t)N * 4);
  unsigned short* B2  = (unsigned short*)alloc((size_t)256 * 256 * 2);
  unsigned short* BT2 = (unsigned short*)alloc((size_t)128 * 128 * 2);
  unsigned short* bufG  = (unsigned short*)alloc((size_t)Mp * 128 * 2);  // h0, then h1W2 (bf16)
  unsigned short* bufH1 = (unsigned short*)alloc((size_t)Mp * 128 * 2);  // h1 bf16
  unsigned short* bufRes = (unsigned short*)alloc((size_t)Mp * 128 * 2); // x@Wres bf16
  (void)ws_size; (void)n_in; (void)out_size;

  int TB = 256;
  hipMemsetAsync(packed, 0, (size_t)N * 8 * 4, stream);
  cast_weights<<<(256 * 256 + 128 * 128 + TB - 1) / TB, TB, 0, stream>>>(W1, Wres, W2, B2, BT2);

  // fused: hist FIRST (blocks [0,hB), 8 edges/thread) + GEMM1 (blocks [hB,..))
  int hB = (E + TB * 8 - 1) / (TB * 8);
  int gB = Mp / 64;
  fused_gemm1_hist<<<hB + gB, TB, 0, stream>>>(x, B2, bufG, bufRes, N,
                                               col, ew, packed, rank, E, hB, N);

  int NV = 8 * N;
  int nb = (NV + SCAN_B * SCAN_I - 1) / (SCAN_B * SCAN_I);
  scanA<<<nb, SCAN_B, 0, stream>>>(packed, dis, cnt, startV, blkSum, N);
  scanB<<<1, 256, 0, stream>>>(blkSum, blkOff, nb);
  place_kernel<<<(E + TB - 1) / TB, TB, 0, stream>>>(row, col, ew, dis, startV, blkOff,
                                                     rank, edges, E);

  // prop1: h1 = relu(bn1(agg(h0) + b1)) -> bufH1 (bf16)
  int propBlocks = (int)(((size_t)N * 64 + TB - 1) / TB);
  prop128_bf16out<<<propBlocks, TB, 0, stream>>>((const unsigned int*)bufG, startV, blkOff, cnt,
                                                 edges, dis, b1, g1, be1, m1, v1,
                                                 (unsigned int*)bufH1, N);

  // GEMM2: h1 @ W2 -> bufG (bf16, reused)
  gemm2_mfma<<<Mp / 128, 256, 0, stream>>>(bufH1, BT2, bufG);

  // prop2 + fused W3: h3 = relu(bn2(agg(h1W2) + b2 + res)) . W3
  prop128_w3out<<<propBlocks, TB, 0, stream>>>((const unsigned int*)bufG, startV, blkOff, cnt,
                                               edges, dis, b2, g2, be2, m2, v2,
                                               (const unsigned int*)bufRes, W3, h3, N);

  // out = agg(h3) + b3 (4 lanes/node)
  prop3_kernel<<<(int)(((size_t)N * 4 + TB - 1) / TB), TB, 0, stream>>>(h3, startV, blkOff, cnt,
                                                                        edges, dis, b3,
                                                                        (float*)d_out, N);
}

// Round 16
// 454.198 us; speedup vs baseline: 2.0716x; 1.0642x over previous
//
#include <hip/hip_runtime.h>
#include <hip/hip_bf16.h>

#define BN_EPS 1e-5f
#define FIX_SCALE 262144.0f

// Edges per chunk-block in count/scatter passes (256 thr x 8 edges)
#define EPB 2048
// Max column-buckets supported (128 cols each): N <= 104448
#define NBK_MAX 816

using short8 = __attribute__((ext_vector_type(8))) short;
using f32x4  = __attribute__((ext_vector_type(4))) float;

static __device__ __forceinline__ unsigned short f2bf(float f) {
  unsigned int u = __float_as_uint(f);
  unsigned int r = (u + 0x7fffu + ((u >> 16) & 1u)) >> 16;
  return (unsigned short)r;
}

// ------------------------------------------------- weight cast
// B2 (GEMM1 weights) fragment-ordered: B2[k>>5][n][k&31]. BT2 (GEMM2) n-major.

static __global__ void cast_weights(const float* __restrict__ W1, const float* __restrict__ Wres,
                                    const float* __restrict__ W2,
                                    unsigned short* __restrict__ B2,
                                    unsigned short* __restrict__ BT2) {
  int i = blockIdx.x * blockDim.x + threadIdx.x;
  if (i < 256 * 256) {
    int n = i >> 8, k = i & 255;
    float v = (n < 128) ? W1[k * 128 + n] : Wres[k * 128 + (n - 128)];
    B2[(k >> 5) * 8192 + n * 32 + (k & 31)] = f2bf(v);
  } else if (i < 256 * 256 + 128 * 128) {
    int j = i - 256 * 256;
    int n = j >> 7, k = j & 127;
    BT2[j] = f2bf(W2[k * 128 + n]);
  }
}

// ---------------------------------------------------------------- fused COUNT + GEMM1
// Count role (blocks [0,CB)): per-chunk LDS histogram of NBK column-buckets
//   (bucket = col>>7). NO global atomics — this replaces the 1.6M returning
//   memory-side RMWs that pinned every prior variant at 115-126us.
// GEMM role (blocks [CB,..)): unchanged R11 structure (A-only LDS dbuf,
//   B frags from L2-resident B2, one-step prefetch).

static __global__ __launch_bounds__(256)
void fused_count_gemm1(const float* __restrict__ A, const unsigned short* __restrict__ B2,
                       unsigned short* __restrict__ C0, unsigned short* __restrict__ C1, int M,
                       const int* __restrict__ col, int* __restrict__ BB,
                       int E, int CB, int NBK) {
  __shared__ unsigned short As[2 * 64 * 40];   // 10KB; count role reuses as uint[NBK]

  int b = blockIdx.x;
  int t = threadIdx.x;
  if (b < CB) {
    unsigned int* cnts = (unsigned int*)As;    // NBK*4 <= 3.3KB < 10KB
    for (int k = t; k < NBK; k += 256) cnts[k] = 0u;
    __syncthreads();
    int base = b * EPB + t;
#pragma unroll
    for (int j = 0; j < 8; ++j) {
      int e = base + j * 256;
      if (e < E) atomicAdd(&cnts[col[e] >> 7], 1u);
    }
    __syncthreads();
    for (int k = t; k < NBK; k += 256) BB[(size_t)b * NBK + k] = (int)cnts[k];
    return;
  }

  // ---------------- gemm role
  int wv = t >> 6, lane = t & 63;
  int quad = lane >> 4, l15 = lane & 15;
  int m0 = (b - CB) * 64;

  f32x4 acc[4][4];
#pragma unroll
  for (int i = 0; i < 4; ++i)
#pragma unroll
    for (int j = 0; j < 4; ++j) acc[i][j] = (f32x4){0.f, 0.f, 0.f, 0.f};

  int ar = t >> 2;
  int ac = (t & 3) * 8;
  bool avalid = (m0 + ar) < M;
  const float* Arow = A + (size_t)(m0 + ar) * 256 + ac;
  const unsigned short* Bfrag = B2 + (wv * 64 + l15) * 32 + quad * 8;

  float4 a0 = make_float4(0.f, 0.f, 0.f, 0.f), a1 = a0;
  if (avalid) {
    a0 = *(const float4*)(Arow + 0);
    a1 = *(const float4*)(Arow + 4);
  }
  {
    short8 av;
    av[0] = (short)f2bf(a0.x); av[1] = (short)f2bf(a0.y);
    av[2] = (short)f2bf(a0.z); av[3] = (short)f2bf(a0.w);
    av[4] = (short)f2bf(a1.x); av[5] = (short)f2bf(a1.y);
    av[6] = (short)f2bf(a1.z); av[7] = (short)f2bf(a1.w);
    *(short8*)&As[ar * 40 + ac] = av;
  }
  short8 bc[4];
#pragma unroll
  for (int nt = 0; nt < 4; ++nt)
    bc[nt] = *(const short8*)(Bfrag + nt * 512);
  __syncthreads();

#pragma unroll 2
  for (int s = 0; s < 8; ++s) {
    int cur = (s & 1) ? 2560 : 0;

    short8 bn[4];
    if (s < 7) {
#pragma unroll
      for (int nt = 0; nt < 4; ++nt)
        bn[nt] = *(const short8*)(Bfrag + (s + 1) * 8192 + nt * 512);
      if (avalid) {
        a0 = *(const float4*)(Arow + (s + 1) * 32);
        a1 = *(const float4*)(Arow + (s + 1) * 32 + 4);
      }
    }

    short8 af[4];
#pragma unroll
    for (int mt = 0; mt < 4; ++mt)
      af[mt] = *(const short8*)&As[cur + (mt * 16 + l15) * 40 + quad * 8];
#pragma unroll
    for (int mt = 0; mt < 4; ++mt)
#pragma unroll
      for (int nt = 0; nt < 4; ++nt)
        acc[mt][nt] = __builtin_amdgcn_mfma_f32_16x16x32_bf16(af[mt], bc[nt], acc[mt][nt], 0, 0, 0);

    if (s < 7) {
      short8 av;
      av[0] = (short)f2bf(a0.x); av[1] = (short)f2bf(a0.y);
      av[2] = (short)f2bf(a0.z); av[3] = (short)f2bf(a0.w);
      av[4] = (short)f2bf(a1.x); av[5] = (short)f2bf(a1.y);
      av[6] = (short)f2bf(a1.z); av[7] = (short)f2bf(a1.w);
      *(short8*)&As[(cur ^ 2560) + ar * 40 + ac] = av;
#pragma unroll
      for (int nt = 0; nt < 4; ++nt) bc[nt] = bn[nt];
    }
    __syncthreads();
  }

  int nbase = wv * 64;
#pragma unroll
  for (int mt = 0; mt < 4; ++mt) {
#pragma unroll
    for (int nt = 0; nt < 4; ++nt) {
      int n = nbase + nt * 16 + l15;
#pragma unroll
      for (int reg = 0; reg < 4; ++reg) {
        size_t m = (size_t)(m0 + mt * 16 + quad * 4 + reg);
        if (nbase < 128) C0[m * 128 + n] = f2bf(acc[mt][nt][reg]);
        else             C1[m * 128 + (n - 128)] = f2bf(acc[mt][nt][reg]);
      }
    }
  }
}

// ---------------------------------------------------------------- bucket scans

// totals[k] = sum over chunks b of BB[b][k]
static __global__ void totals_kernel(const int* __restrict__ BB, int* __restrict__ total,
                                     int CB, int NBK) {
  __shared__ int sh[256];
  int k = blockIdx.x;
  int t = threadIdx.x;
  int part = 0;
  for (int b = t; b < CB; b += 256) part += BB[(size_t)b * NBK + k];
  sh[t] = part;
  __syncthreads();
  for (int off = 128; off > 0; off >>= 1) {
    if (t < off) sh[t] += sh[t + off];
    __syncthreads();
  }
  if (t == 0) total[k] = sh[0];
}

// bucketBase = exclusive scan of totals; bucketBase[NBK] = E
static __global__ void base_kernel(const int* __restrict__ total, int* __restrict__ bucketBase,
                                   int NBK) {
  __shared__ int sh[256];
  __shared__ int carrySh;
  int t = threadIdx.x;
  if (t == 0) carrySh = 0;
  __syncthreads();
  for (int c0 = 0; c0 < NBK; c0 += 256) {
    int i = c0 + t;
    int v = (i < NBK) ? total[i] : 0;
    sh[t] = v;
    __syncthreads();
    for (int off = 1; off < 256; off <<= 1) {
      int add = (t >= off) ? sh[t - off] : 0;
      __syncthreads();
      sh[t] += add;
      __syncthreads();
    }
    if (i < NBK) bucketBase[i] = carrySh + sh[t] - v;
    __syncthreads();
    if (t == 0) carrySh += sh[255];
    __syncthreads();
  }
  if (t == 0) bucketBase[NBK] = carrySh;
}

// BB[b][k] <- bucketBase[k] + exclusive-scan over b of BB[b][k]  (global cursor bases)
static __global__ void off_kernel(int* __restrict__ BB, const int* __restrict__ bucketBase,
                                  int CB, int NBK) {
  __shared__ int sh[256];
  __shared__ int carrySh;
  int k = blockIdx.x;
  int t = threadIdx.x;
  if (t == 0) carrySh = bucketBase[k];
  __syncthreads();
  for (int b0 = 0; b0 < CB; b0 += 256) {
    int b = b0 + t;
    int v = (b < CB) ? BB[(size_t)b * NBK + k] : 0;
    sh[t] = v;
    __syncthreads();
    for (int off = 1; off < 256; off <<= 1) {
      int add = (t >= off) ? sh[t - off] : 0;
      __syncthreads();
      sh[t] += add;
      __syncthreads();
    }
    if (b < CB) BB[(size_t)b * NBK + k] = carrySh + sh[t] - v;
    __syncthreads();
    if (t == 0) carrySh += sh[255];
    __syncthreads();
  }
}

// ---------------------------------------------------------------- scatter into buckets
// tmp[pos] = (ew_bits<<32) | (c&127)<<17 | r   — positions from LDS cursors (no global atomics)
static __global__ void scatter_kernel(const int* __restrict__ row, const int* __restrict__ col,
                                      const float* __restrict__ ew, const int* __restrict__ BB,
                                      unsigned long long* __restrict__ tmp, int E, int NBK) {
  __shared__ unsigned int cur[NBK_MAX];
  int b = blockIdx.x;
  int t = threadIdx.x;
  for (int k = t; k < NBK; k += 256) cur[k] = (unsigned int)BB[(size_t)b * NBK + k];
  __syncthreads();
  int base = b * EPB + t;
#pragma unroll
  for (int j = 0; j < 8; ++j) {
    int e = base + j * 256;
    if (e < E) {
      int c = col[e];
      int k = c >> 7;
      unsigned int pos = atomicAdd(&cur[k], 1u);
      unsigned int lo = (unsigned int)row[e] | ((unsigned int)(c & 127) << 17);
      unsigned long long w = ((unsigned long long)__float_as_uint(ew[e]) << 32) | lo;
      tmp[pos] = w;
    }
  }
}

// ---------------------------------------------------------------- per-bucket CSR build
// Block k owns columns [k*128, k*128+128) and tmp segment [base[k], base[k+1]).
// LDS count + scan + LDS-cursor placement -> exact start/cnt/dis + final slots.
static __global__ void bucket_csr(const unsigned long long* __restrict__ tmp,
                                  const int* __restrict__ bucketBase,
                                  int* __restrict__ cnt, int* __restrict__ start,
                                  float* __restrict__ dis,
                                  unsigned long long* __restrict__ edges, int N) {
  __shared__ unsigned int colCnt[128];
  __shared__ unsigned int sumEw[128];
  __shared__ int so[128];
  int k = blockIdx.x;
  int t = threadIdx.x;
  int segBase = bucketBase[k], segEnd = bucketBase[k + 1];
  int segN = segEnd - segBase;

  if (t < 128) { colCnt[t] = 0u; sumEw[t] = 0u; }
  __syncthreads();

  for (int i = t; i < segN; i += 256) {
    unsigned long long w = tmp[segBase + i];
    unsigned int lo = (unsigned int)w;
    int cl = (int)((lo >> 17) & 127u);
    float ewv = __uint_as_float((unsigned int)(w >> 32));
    atomicAdd(&colCnt[cl], 1u);
    atomicAdd(&sumEw[cl], (unsigned int)(ewv * FIX_SCALE + 0.5f));
  }
  __syncthreads();

  // inclusive scan of colCnt into so
  if (t < 128) so[t] = (int)colCnt[t];
  __syncthreads();
  for (int off = 1; off < 128; off <<= 1) {
    int add = (t >= off && t < 128) ? so[t - off] : 0;
    __syncthreads();
    if (t < 128) so[t] += add;
    __syncthreads();
  }

  if (t < 128) {
    int excl = so[t] - (int)colCnt[t];
    int c = k * 128 + t;
    if (c < N) {
      cnt[c] = (int)colCnt[t];
      start[c] = segBase + excl;
      dis[c] = rsqrtf(1.0f + (float)sumEw[t] * (1.0f / FIX_SCALE));
    }
    colCnt[t] = (unsigned int)excl;   // becomes the placement cursor
  }
  __syncthreads();

  for (int i = t; i < segN; i += 256) {
    unsigned long long w = tmp[segBase + i];
    unsigned int lo = (unsigned int)w;
    int cl = (int)((lo >> 17) & 127u);
    unsigned int p = atomicAdd(&colCnt[cl], 1u);
    edges[segBase + (int)p] = (w & 0xffffffff00000000ull) | (unsigned long long)(lo & 0x1ffffu);
  }
}

// finalize: edges[i] = (float_bits(dis[r]*ew) << 32) | r
static __global__ void finalize_kernel(unsigned long long* __restrict__ edges,
                                       const float* __restrict__ dis, int E) {
  int i = blockIdx.x * blockDim.x + threadIdx.x;
  if (i < E) {
    unsigned long long w = edges[i];
    int r = (int)(unsigned int)(w & 0xffffffffull);
    float ewv = __uint_as_float((unsigned int)(w >> 32));
    float nrm = dis[r] * ewv;
    edges[i] = ((unsigned long long)__float_as_uint(nrm) << 32) | (unsigned int)r;
  }
}

// ---------------------------------------------------------------- GEMM2 (row-major, LDS-staged)

static __global__ __launch_bounds__(256)
void gemm2_mfma(const unsigned short* __restrict__ A, const unsigned short* __restrict__ BT,
                unsigned short* __restrict__ C) {
  __shared__ unsigned short As[128 * 40];
  __shared__ unsigned short Bs[128 * 40];
  int t = threadIdx.x;
  int wv = t >> 6, lane = t & 63;
  int quad = lane >> 4, l15 = lane & 15;
  int m0 = blockIdx.x * 128;

  f32x4 acc[4][4];
#pragma unroll
  for (int i = 0; i < 4; ++i)
#pragma unroll
    for (int j = 0; j < 4; ++j) acc[i][j] = (f32x4){0.f, 0.f, 0.f, 0.f};

  int sr = t >> 1, sc = (t & 1) * 16;

  for (int k0 = 0; k0 < 128; k0 += 32) {
    short8 a0 = *(const short8*)(A + (size_t)(m0 + sr) * 128 + k0 + sc);
    short8 a1 = *(const short8*)(A + (size_t)(m0 + sr) * 128 + k0 + sc + 8);
    *(short8*)&As[sr * 40 + sc]     = a0;
    *(short8*)&As[sr * 40 + sc + 8] = a1;
    short8 b0 = *(const short8*)(BT + (size_t)sr * 128 + k0 + sc);
    short8 b1 = *(const short8*)(BT + (size_t)sr * 128 + k0 + sc + 8);
    *(short8*)&Bs[sr * 40 + sc]     = b0;
    *(short8*)&Bs[sr * 40 + sc + 8] = b1;
    __syncthreads();

    int mb = (wv >> 1) * 64, nb = (wv & 1) * 64;
    short8 af[4], bf[4];
#pragma unroll
    for (int mt = 0; mt < 4; ++mt)
      af[mt] = *(const short8*)&As[(mb + mt * 16 + l15) * 40 + quad * 8];
#pragma unroll
    for (int nt = 0; nt < 4; ++nt)
      bf[nt] = *(const short8*)&Bs[(nb + nt * 16 + l15) * 40 + quad * 8];
#pragma unroll
    for (int mt = 0; mt < 4; ++mt)
#pragma unroll
      for (int nt = 0; nt < 4; ++nt)
        acc[mt][nt] = __builtin_amdgcn_mfma_f32_16x16x32_bf16(af[mt], bf[nt], acc[mt][nt], 0, 0, 0);
    __syncthreads();
  }

  int mb = (wv >> 1) * 64, nb = (wv & 1) * 64;
#pragma unroll
  for (int mt = 0; mt < 4; ++mt)
#pragma unroll
    for (int nt = 0; nt < 4; ++nt) {
      int n = nb + nt * 16 + l15;
#pragma unroll
      for (int reg = 0; reg < 4; ++reg) {
        size_t m = (size_t)(m0 + mb + mt * 16 + quad * 4 + reg);
        C[m * 128 + n] = f2bf(acc[mt][nt][reg]);
      }
    }
}

// ---------------------------------------------------------------- propagation core (row-major)
// One wave per destination node; lane holds 2 channels. 8 coalesced 256B row
// gathers in flight per chunk. start/cnt are exact CSR now (sort-built).

#define PROP_GATHER_BODY                                                        \
  int c0 = lane * 2;                                                            \
  float d = dis[w];                                                             \
  float acc0, acc1;                                                             \
  {                                                                             \
    unsigned int u = Hsrc[(size_t)w * 64 + lane];                               \
    acc0 = d * __uint_as_float(u << 16);                                        \
    acc1 = d * __uint_as_float(u & 0xffff0000u);                                \
  }                                                                             \
  int s = start[w], n = cnt[w];                                                 \
  int k = 0;                                                                    \
  while (k < n) {                                                               \
    int chunk = min(n - k, 64);                                                 \
    int idx = 0;                                                                \
    float wt = 0.f;                                                             \
    if (lane < chunk) {                                                         \
      long long ev = (long long)edges[s + k + lane];                            \
      idx = (int)(unsigned int)(ev & 0xffffffffLL);                             \
      wt  = __int_as_float((int)(ev >> 32));                                    \
    }                                                                           \
    for (int j = 0; j < chunk; j += 8) {                                        \
      int   i0 = __shfl(idx, j + 0, 64), i1 = __shfl(idx, j + 1, 64);           \
      int   i2 = __shfl(idx, j + 2, 64), i3 = __shfl(idx, j + 3, 64);           \
      int   i4 = __shfl(idx, j + 4, 64), i5 = __shfl(idx, j + 5, 64);           \
      int   i6 = __shfl(idx, j + 6, 64), i7 = __shfl(idx, j + 7, 64);           \
      float w0 = __shfl(wt, j + 0, 64), w1 = __shfl(wt, j + 1, 64);             \
      float w2 = __shfl(wt, j + 2, 64), w3 = __shfl(wt, j + 3, 64);             \
      float w4 = __shfl(wt, j + 4, 64), w5 = __shfl(wt, j + 5, 64);             \
      float w6 = __shfl(wt, j + 6, 64), w7 = __shfl(wt, j + 7, 64);             \
      unsigned int u0 = Hsrc[(size_t)i0 * 64 + lane];                           \
      unsigned int u1 = Hsrc[(size_t)i1 * 64 + lane];                           \
      unsigned int u2 = Hsrc[(size_t)i2 * 64 + lane];                           \
      unsigned int u3 = Hsrc[(size_t)i3 * 64 + lane];                           \
      unsigned int u4 = Hsrc[(size_t)i4 * 64 + lane];                           \
      unsigned int u5 = Hsrc[(size_t)i5 * 64 + lane];                           \
      unsigned int u6 = Hsrc[(size_t)i6 * 64 + lane];                           \
      unsigned int u7 = Hsrc[(size_t)i7 * 64 + lane];                           \
      acc0 = fmaf(w0, __uint_as_float(u0 << 16), acc0);                         \
      acc1 = fmaf(w0, __uint_as_float(u0 & 0xffff0000u), acc1);                 \
      acc0 = fmaf(w1, __uint_as_float(u1 << 16), acc0);                         \
      acc1 = fmaf(w1, __uint_as_float(u1 & 0xffff0000u), acc1);                 \
      acc0 = fmaf(w2, __uint_as_float(u2 << 16), acc0);                         \
      acc1 = fmaf(w2, __uint_as_float(u2 & 0xffff0000u), acc1);                 \
      acc0 = fmaf(w3, __uint_as_float(u3 << 16), acc0);                         \
      acc1 = fmaf(w3, __uint_as_float(u3 & 0xffff0000u), acc1);                 \
      acc0 = fmaf(w4, __uint_as_float(u4 << 16), acc0);                         \
      acc1 = fmaf(w4, __uint_as_float(u4 & 0xffff0000u), acc1);                 \
      acc0 = fmaf(w5, __uint_as_float(u5 << 16), acc0);                         \
      acc1 = fmaf(w5, __uint_as_float(u5 & 0xffff0000u), acc1);                 \
      acc0 = fmaf(w6, __uint_as_float(u6 << 16), acc0);                         \
      acc1 = fmaf(w6, __uint_as_float(u6 & 0xffff0000u), acc1);                 \
      acc0 = fmaf(w7, __uint_as_float(u7 << 16), acc0);                         \
      acc1 = fmaf(w7, __uint_as_float(u7 & 0xffff0000u), acc1);                 \
    }                                                                           \
    k += chunk;                                                                 \
  }                                                                             \
  acc0 *= d;                                                                    \
  acc1 *= d;

static __global__ __launch_bounds__(256)
void prop128_bf16out(const unsigned int* __restrict__ Hsrc,
                     const int* __restrict__ start, const int* __restrict__ cnt,
                     const unsigned long long* __restrict__ edges,
                     const float* __restrict__ dis,
                     const float* __restrict__ bvec,
                     const float* __restrict__ g, const float* __restrict__ be,
                     const float* __restrict__ mean, const float* __restrict__ var,
                     unsigned int* __restrict__ Outb, int N) {
  int w = (int)((blockIdx.x * blockDim.x + threadIdx.x) >> 6);
  int lane = threadIdx.x & 63;
  if (w >= N) return;
  PROP_GATHER_BODY
  float x0 = acc0 + bvec[c0];
  float x1 = acc1 + bvec[c0 + 1];
  float s0 = g[c0] * rsqrtf(var[c0] + BN_EPS);
  float s1 = g[c0 + 1] * rsqrtf(var[c0 + 1] + BN_EPS);
  x0 = fmaxf((x0 - mean[c0]) * s0 + be[c0], 0.f);
  x1 = fmaxf((x1 - mean[c0 + 1]) * s1 + be[c0 + 1], 0.f);
  unsigned int packed = (unsigned int)f2bf(x0) | ((unsigned int)f2bf(x1) << 16);
  Outb[(size_t)w * 64 + lane] = packed;
}

static __global__ __launch_bounds__(256)
void prop128_w3out(const unsigned int* __restrict__ Hsrc,
                   const int* __restrict__ start, const int* __restrict__ cnt,
                   const unsigned long long* __restrict__ edges,
                   const float* __restrict__ dis,
                   const float* __restrict__ bvec,
                   const float* __restrict__ g, const float* __restrict__ be,
                   const float* __restrict__ mean, const float* __restrict__ var,
                   const unsigned int* __restrict__ resb, const float* __restrict__ W3,
                   float* __restrict__ h3, int N) {
  int w = (int)((blockIdx.x * blockDim.x + threadIdx.x) >> 6);
  int lane = threadIdx.x & 63;
  if (w >= N) return;
  PROP_GATHER_BODY
  unsigned int ru = resb[(size_t)w * 64 + lane];
  float x0 = acc0 + bvec[c0]     + __uint_as_float(ru << 16);
  float x1 = acc1 + bvec[c0 + 1] + __uint_as_float(ru & 0xffff0000u);
  float s0 = g[c0] * rsqrtf(var[c0] + BN_EPS);
  float s1 = g[c0 + 1] * rsqrtf(var[c0 + 1] + BN_EPS);
  x0 = fmaxf((x0 - mean[c0]) * s0 + be[c0], 0.f);
  x1 = fmaxf((x1 - mean[c0 + 1]) * s1 + be[c0 + 1], 0.f);
  float v = x0 * W3[c0] + x1 * W3[c0 + 1];
#pragma unroll
  for (int off = 32; off > 0; off >>= 1) v += __shfl_down(v, off, 64);
  if (lane == 0) h3[w] = v;
}

// ---------------------------------------------------------------- final 1-wide propagation

static __global__ __launch_bounds__(256)
void prop3_kernel(const float* __restrict__ h3,
                  const int* __restrict__ start, const int* __restrict__ cnt,
                  const unsigned long long* __restrict__ edges,
                  const float* __restrict__ dis, const float* __restrict__ b3,
                  float* __restrict__ out, int N) {
  int tid = blockIdx.x * blockDim.x + threadIdx.x;
  int i = tid >> 2;
  int sub = tid & 3;
  if (i >= N) return;
  float acc = 0.f;
  int s = start[i], n = cnt[i];
  for (int k = sub; k < n; k += 4) {
    unsigned long long ev = edges[s + k];
    int src = (int)(unsigned int)(ev & 0xffffffffull);
    float wt = __uint_as_float((unsigned int)(ev >> 32));
    acc = fmaf(wt, h3[src], acc);
  }
  acc += __shfl_xor(acc, 1, 64);
  acc += __shfl_xor(acc, 2, 64);
  if (sub == 0) {
    float d = dis[i];
    out[i] = (acc + d * h3[i]) * d + b3[0];
  }
}

// ---------------------------------------------------------------- launch

extern "C" void kernel_launch(void* const* d_in, const int* in_sizes, int n_in,
                              void* d_out, int out_size, void* d_ws, size_t ws_size,
                              hipStream_t stream) {
  const float* x    = (const float*)d_in[0];
  const int*   ei   = (const int*)d_in[1];
  const float* ew   = (const float*)d_in[2];
  const float* W1   = (const float*)d_in[3];
  const float* b1   = (const float*)d_in[4];
  const float* W2   = (const float*)d_in[5];
  const float* b2   = (const float*)d_in[6];
  const float* W3   = (const float*)d_in[7];
  const float* b3   = (const float*)d_in[8];
  const float* Wres = (const float*)d_in[9];
  const float* g1   = (const float*)d_in[10];
  const float* be1  = (const float*)d_in[11];
  const float* m1   = (const float*)d_in[12];
  const float* v1   = (const float*)d_in[13];
  const float* g2   = (const float*)d_in[14];
  const float* be2  = (const float*)d_in[15];
  const float* m2   = (const float*)d_in[16];
  const float* v2   = (const float*)d_in[17];

  int Hh = in_sizes[4];            // 128
  int V  = in_sizes[3] / Hh;       // 256
  int N  = in_sizes[0] / V;        // 100000
  int E  = in_sizes[2];            // 1600000
  const int* row = ei;
  const int* col = ei + E;

  int Mp = ((N + 127) / 128) * 128;
  int CB  = (E + EPB - 1) / EPB;   // chunk blocks (count/scatter)
  int NBK = (N + 127) >> 7;        // column buckets (128 cols each)

  char* p = (char*)d_ws;
  auto alloc = [&](size_t bytes) -> char* {
    char* r = p;
    p += (bytes + 255) & ~(size_t)255;
    return r;
  };
  int*   BB     = (int*)alloc((size_t)CB * NBK * 4);   // counts -> cursor bases
  int*   total  = (int*)alloc((size_t)NBK * 4);
  int*   bucketBase = (int*)alloc((size_t)(NBK + 1) * 4);
  float* dis    = (float*)alloc((size_t)N * 4);
  int*   cnt    = (int*)  alloc((size_t)N * 4);
  int*   startA = (int*)  alloc((size_t)N * 4);
  unsigned long long* tmp   = (unsigned long long*)alloc((size_t)E * 8);
  unsigned long long* edges = (unsigned long long*)alloc((size_t)E * 8);
  float* h3     = (float*)alloc((size_t)N * 4);
  unsigned short* B2  = (unsigned short*)alloc((size_t)256 * 256 * 2);
  unsigned short* BT2 = (unsigned short*)alloc((size_t)128 * 128 * 2);
  unsigned short* bufG  = (unsigned short*)alloc((size_t)Mp * 128 * 2);  // h0, then h1W2 (bf16)
  unsigned short* bufH1 = (unsigned short*)alloc((size_t)Mp * 128 * 2);  // h1 bf16
  unsigned short* bufRes = (unsigned short*)alloc((size_t)Mp * 128 * 2); // x@Wres bf16
  (void)ws_size; (void)n_in; (void)out_size;

  int TB = 256;
  cast_weights<<<(256 * 256 + 128 * 128 + TB - 1) / TB, TB, 0, stream>>>(W1, Wres, W2, B2, BT2);

  // fused: bucket-count (blocks [0,CB)) + GEMM1 (blocks [CB,..))
  int gB = Mp / 64;
  fused_count_gemm1<<<CB + gB, TB, 0, stream>>>(x, B2, bufG, bufRes, N,
                                                col, BB, E, CB, NBK);

  totals_kernel<<<NBK, 256, 0, stream>>>(BB, total, CB, NBK);
  base_kernel<<<1, 256, 0, stream>>>(total, bucketBase, NBK);
  off_kernel<<<NBK, 256, 0, stream>>>(BB, bucketBase, CB, NBK);
  scatter_kernel<<<CB, 256, 0, stream>>>(row, col, ew, BB, tmp, E, NBK);
  bucket_csr<<<NBK, 256, 0, stream>>>(tmp, bucketBase, cnt, startA, dis, edges, N);
  finalize_kernel<<<(E + 255) / 256, 256, 0, stream>>>(edges, dis, E);

  // prop1: h1 = relu(bn1(agg(h0) + b1)) -> bufH1 (bf16)
  int propBlocks = (int)(((size_t)N * 64 + TB - 1) / TB);
  prop128_bf16out<<<propBlocks, TB, 0, stream>>>((const unsigned int*)bufG, startA, cnt,
                                                 edges, dis, b1, g1, be1, m1, v1,
                                                 (unsigned int*)bufH1, N);

  // GEMM2: h1 @ W2 -> bufG (bf16, reused)
  gemm2_mfma<<<Mp / 128, 256, 0, stream>>>(bufH1, BT2, bufG);

  // prop2 + fused W3: h3 = relu(bn2(agg(h1W2) + b2 + res)) . W3
  prop128_w3out<<<propBlocks, TB, 0, stream>>>((const unsigned int*)bufG, startA, cnt,
                                               edges, dis, b2, g2, be2, m2, v2,
                                               (const unsigned int*)bufRes, W3, h3, N);

  // out = agg(h3) + b3 (4 lanes/node)
  prop3_kernel<<<(int)(((size_t)N * 4 + TB - 1) / TB), TB, 0, stream>>>(h3, startA, cnt,
                                                                        edges, dis, b3,
                                                                        (float*)d_out, N);
}

// Round 18
// 450.219 us; speedup vs baseline: 2.0899x; 1.0088x over previous
//
#include <hip/hip_runtime.h>
#include <hip/hip_bf16.h>

#define BN_EPS 1e-5f
#define FIX_SCALE 262144.0f

// Edges per chunk-block in count/scatter passes (256 thr x 8 edges)
#define EPB 2048
// Max column-buckets supported (128 cols each): N <= 104448
#define NBK_MAX 816

using short8 = __attribute__((ext_vector_type(8))) short;
using f32x4  = __attribute__((ext_vector_type(4))) float;

static __device__ __forceinline__ unsigned short f2bf(float f) {
  unsigned int u = __float_as_uint(f);
  unsigned int r = (u + 0x7fffu + ((u >> 16) & 1u)) >> 16;
  return (unsigned short)r;
}

// ------------------------------------------------- weight cast
// B2 (GEMM1 weights) fragment-ordered: B2[k>>5][n][k&31]. BT2 (GEMM2) n-major.

static __global__ void cast_weights(const float* __restrict__ W1, const float* __restrict__ Wres,
                                    const float* __restrict__ W2,
                                    unsigned short* __restrict__ B2,
                                    unsigned short* __restrict__ BT2) {
  int i = blockIdx.x * blockDim.x + threadIdx.x;
  if (i < 256 * 256) {
    int n = i >> 8, k = i & 255;
    float v = (n < 128) ? W1[k * 128 + n] : Wres[k * 128 + (n - 128)];
    B2[(k >> 5) * 8192 + n * 32 + (k & 31)] = f2bf(v);
  } else if (i < 256 * 256 + 128 * 128) {
    int j = i - 256 * 256;
    int n = j >> 7, k = j & 127;
    BT2[j] = f2bf(W2[k * 128 + n]);
  }
}

// ---------------------------------------------------------------- fused COUNT + GEMM1
// Count role (blocks [0,CB)): per-chunk LDS histogram of NBK column-buckets,
//   written TRANSPOSED: BBt[k*CB + b] so totals/off scans are coalesced.
// GEMM role (blocks [CB,..)): A-only LDS dbuf with COMMIT-AT-TOP 2-deep A
//   pipeline (R16: load->use gap was only ~1 MFMA block; now a full k-step).

static __global__ __launch_bounds__(256)
void fused_count_gemm1(const float* __restrict__ A, const unsigned short* __restrict__ B2,
                       unsigned short* __restrict__ C0, unsigned short* __restrict__ C1, int M,
                       const int* __restrict__ col, int* __restrict__ BBt,
                       int E, int CB, int NBK) {
  __shared__ unsigned short As[2 * 64 * 40];   // 10KB; count role reuses as uint[NBK]

  int b = blockIdx.x;
  int t = threadIdx.x;
  if (b < CB) {
    unsigned int* cnts = (unsigned int*)As;    // NBK*4 <= 3.3KB < 10KB
    for (int k = t; k < NBK; k += 256) cnts[k] = 0u;
    __syncthreads();
    int base = b * EPB + t;
#pragma unroll
    for (int j = 0; j < 8; ++j) {
      int e = base + j * 256;
      if (e < E) atomicAdd(&cnts[col[e] >> 7], 1u);
    }
    __syncthreads();
    for (int k = t; k < NBK; k += 256) BBt[(size_t)k * CB + b] = (int)cnts[k];
    return;
  }

  // ---------------- gemm role
  int wv = t >> 6, lane = t & 63;
  int quad = lane >> 4, l15 = lane & 15;
  int m0 = (b - CB) * 64;

  f32x4 acc[4][4];
#pragma unroll
  for (int i = 0; i < 4; ++i)
#pragma unroll
    for (int j = 0; j < 4; ++j) acc[i][j] = (f32x4){0.f, 0.f, 0.f, 0.f};

  int ar = t >> 2;
  int ac = (t & 3) * 8;
  bool avalid = (m0 + ar) < M;
  const float* Arow = A + (size_t)(m0 + ar) * 256 + ac;
  const unsigned short* Bfrag = B2 + (wv * 64 + l15) * 32 + quad * 8;

  // prologue: load+commit panel 0; load panel 1 into regs; preload B frags s=0
  float4 a0 = make_float4(0.f, 0.f, 0.f, 0.f), a1 = a0;
  if (avalid) {
    a0 = *(const float4*)(Arow + 0);
    a1 = *(const float4*)(Arow + 4);
  }
  {
    short8 av;
    av[0] = (short)f2bf(a0.x); av[1] = (short)f2bf(a0.y);
    av[2] = (short)f2bf(a0.z); av[3] = (short)f2bf(a0.w);
    av[4] = (short)f2bf(a1.x); av[5] = (short)f2bf(a1.y);
    av[6] = (short)f2bf(a1.z); av[7] = (short)f2bf(a1.w);
    *(short8*)&As[ar * 40 + ac] = av;
  }
  if (avalid) {
    a0 = *(const float4*)(Arow + 32);
    a1 = *(const float4*)(Arow + 36);
  }
  short8 bc[4];
#pragma unroll
  for (int nt = 0; nt < 4; ++nt)
    bc[nt] = *(const short8*)(Bfrag + nt * 512);
  __syncthreads();

  // invariant at top of step s: LDS[cur]=panel s (ready); regs=(panel s+1 raw)
#pragma unroll 2
  for (int s = 0; s < 8; ++s) {
    int cur = (s & 1) ? 2560 : 0;

    // commit panel s+1 (loaded during step s-1; a full step of load latency
    // has elapsed) and immediately issue panel s+2's loads
    if (s < 7) {
      short8 av;
      av[0] = (short)f2bf(a0.x); av[1] = (short)f2bf(a0.y);
      av[2] = (short)f2bf(a0.z); av[3] = (short)f2bf(a0.w);
      av[4] = (short)f2bf(a1.x); av[5] = (short)f2bf(a1.y);
      av[6] = (short)f2bf(a1.z); av[7] = (short)f2bf(a1.w);
      *(short8*)&As[(cur ^ 2560) + ar * 40 + ac] = av;
      if (s < 6 && avalid) {
        a0 = *(const float4*)(Arow + (s + 2) * 32);
        a1 = *(const float4*)(Arow + (s + 2) * 32 + 4);
      }
    }

    // prefetch next panel's B frags (consumed next step)
    short8 bn[4];
    if (s < 7) {
#pragma unroll
      for (int nt = 0; nt < 4; ++nt)
        bn[nt] = *(const short8*)(Bfrag + (s + 1) * 8192 + nt * 512);
    }

    short8 af[4];
#pragma unroll
    for (int mt = 0; mt < 4; ++mt)
      af[mt] = *(const short8*)&As[cur + (mt * 16 + l15) * 40 + quad * 8];
#pragma unroll
    for (int mt = 0; mt < 4; ++mt)
#pragma unroll
      for (int nt = 0; nt < 4; ++nt)
        acc[mt][nt] = __builtin_amdgcn_mfma_f32_16x16x32_bf16(af[mt], bc[nt], acc[mt][nt], 0, 0, 0);

    if (s < 7) {
#pragma unroll
      for (int nt = 0; nt < 4; ++nt) bc[nt] = bn[nt];
    }
    __syncthreads();
  }

  int nbase = wv * 64;
#pragma unroll
  for (int mt = 0; mt < 4; ++mt) {
#pragma unroll
    for (int nt = 0; nt < 4; ++nt) {
      int n = nbase + nt * 16 + l15;
#pragma unroll
      for (int reg = 0; reg < 4; ++reg) {
        size_t m = (size_t)(m0 + mt * 16 + quad * 4 + reg);
        if (nbase < 128) C0[m * 128 + n] = f2bf(acc[mt][nt][reg]);
        else             C1[m * 128 + (n - 128)] = f2bf(acc[mt][nt][reg]);
      }
    }
  }
}

// ---------------------------------------------------------------- bucket scans (BBt coalesced)

// total[k] = sum over chunks b of BBt[k][b]  (contiguous reads)
static __global__ void totals_kernel(const int* __restrict__ BBt, int* __restrict__ total,
                                     int CB, int NBK) {
  __shared__ int sh[256];
  int k = blockIdx.x;
  int t = threadIdx.x;
  int part = 0;
  for (int b = t; b < CB; b += 256) part += BBt[(size_t)k * CB + b];
  sh[t] = part;
  __syncthreads();
  for (int off = 128; off > 0; off >>= 1) {
    if (t < off) sh[t] += sh[t + off];
    __syncthreads();
  }
  if (t == 0) total[k] = sh[0];
}

// bucketBase = exclusive scan of totals; bucketBase[NBK] = E
static __global__ void base_kernel(const int* __restrict__ total, int* __restrict__ bucketBase,
                                   int NBK) {
  __shared__ int sh[256];
  __shared__ int carrySh;
  int t = threadIdx.x;
  if (t == 0) carrySh = 0;
  __syncthreads();
  for (int c0 = 0; c0 < NBK; c0 += 256) {
    int i = c0 + t;
    int v = (i < NBK) ? total[i] : 0;
    sh[t] = v;
    __syncthreads();
    for (int off = 1; off < 256; off <<= 1) {
      int add = (t >= off) ? sh[t - off] : 0;
      __syncthreads();
      sh[t] += add;
      __syncthreads();
    }
    if (i < NBK) bucketBase[i] = carrySh + sh[t] - v;
    __syncthreads();
    if (t == 0) carrySh += sh[255];
    __syncthreads();
  }
  if (t == 0) bucketBase[NBK] = carrySh;
}

// BBt[k][b] <- bucketBase[k] + exclusive-scan over b (contiguous, in-place)
static __global__ void off_kernel(int* __restrict__ BBt, const int* __restrict__ bucketBase,
                                  int CB, int NBK) {
  __shared__ int sh[256];
  __shared__ int carrySh;
  int k = blockIdx.x;
  int t = threadIdx.x;
  if (t == 0) carrySh = bucketBase[k];
  __syncthreads();
  for (int b0 = 0; b0 < CB; b0 += 256) {
    int b = b0 + t;
    int v = (b < CB) ? BBt[(size_t)k * CB + b] : 0;
    sh[t] = v;
    __syncthreads();
    for (int off = 1; off < 256; off <<= 1) {
      int add = (t >= off) ? sh[t - off] : 0;
      __syncthreads();
      sh[t] += add;
      __syncthreads();
    }
    if (b < CB) BBt[(size_t)k * CB + b] = carrySh + sh[t] - v;
    __syncthreads();
    if (t == 0) carrySh += sh[255];
    __syncthreads();
  }
}

// ---------------------------------------------------------------- scatter into buckets
// tmp[pos] = (ew_bits<<32) | (c&127)<<17 | r   — positions from LDS cursors.
// Cursor load is strided over L3-resident BBt (2.5MB) — acceptable.
static __global__ void scatter_kernel(const int* __restrict__ row, const int* __restrict__ col,
                                      const float* __restrict__ ew, const int* __restrict__ BBt,
                                      unsigned long long* __restrict__ tmp, int E, int CB, int NBK) {
  __shared__ unsigned int cur[NBK_MAX];
  int b = blockIdx.x;
  int t = threadIdx.x;
  for (int k = t; k < NBK; k += 256) cur[k] = (unsigned int)BBt[(size_t)k * CB + b];
  __syncthreads();
  int base = b * EPB + t;
#pragma unroll
  for (int j = 0; j < 8; ++j) {
    int e = base + j * 256;
    if (e < E) {
      int c = col[e];
      int k = c >> 7;
      unsigned int pos = atomicAdd(&cur[k], 1u);
      unsigned int lo = (unsigned int)row[e] | ((unsigned int)(c & 127) << 17);
      unsigned long long w = ((unsigned long long)__float_as_uint(ew[e]) << 32) | lo;
      tmp[pos] = w;
    }
  }
}

// ---------------------------------------------------------------- per-bucket CSR build
static __global__ void bucket_csr(const unsigned long long* __restrict__ tmp,
                                  const int* __restrict__ bucketBase,
                                  int* __restrict__ cnt, int* __restrict__ start,
                                  float* __restrict__ dis,
                                  unsigned long long* __restrict__ edges, int N) {
  __shared__ unsigned int colCnt[128];
  __shared__ unsigned int sumEw[128];
  __shared__ int so[128];
  int k = blockIdx.x;
  int t = threadIdx.x;
  int segBase = bucketBase[k], segEnd = bucketBase[k + 1];
  int segN = segEnd - segBase;

  if (t < 128) { colCnt[t] = 0u; sumEw[t] = 0u; }
  __syncthreads();

  for (int i = t; i < segN; i += 256) {
    unsigned long long w = tmp[segBase + i];
    unsigned int lo = (unsigned int)w;
    int cl = (int)((lo >> 17) & 127u);
    float ewv = __uint_as_float((unsigned int)(w >> 32));
    atomicAdd(&colCnt[cl], 1u);
    atomicAdd(&sumEw[cl], (unsigned int)(ewv * FIX_SCALE + 0.5f));
  }
  __syncthreads();

  if (t < 128) so[t] = (int)colCnt[t];
  __syncthreads();
  for (int off = 1; off < 128; off <<= 1) {
    int add = (t >= off && t < 128) ? so[t - off] : 0;
    __syncthreads();
    if (t < 128) so[t] += add;
    __syncthreads();
  }

  if (t < 128) {
    int excl = so[t] - (int)colCnt[t];
    int c = k * 128 + t;
    if (c < N) {
      cnt[c] = (int)colCnt[t];
      start[c] = segBase + excl;
      dis[c] = rsqrtf(1.0f + (float)sumEw[t] * (1.0f / FIX_SCALE));
    }
    colCnt[t] = (unsigned int)excl;   // becomes the placement cursor
  }
  __syncthreads();

  for (int i = t; i < segN; i += 256) {
    unsigned long long w = tmp[segBase + i];
    unsigned int lo = (unsigned int)w;
    int cl = (int)((lo >> 17) & 127u);
    unsigned int p = atomicAdd(&colCnt[cl], 1u);
    edges[segBase + (int)p] = (w & 0xffffffff00000000ull) | (unsigned long long)(lo & 0x1ffffu);
  }
}

// finalize: edges[i] = (float_bits(dis[r]*ew) << 32) | r
static __global__ void finalize_kernel(unsigned long long* __restrict__ edges,
                                       const float* __restrict__ dis, int E) {
  int i = blockIdx.x * blockDim.x + threadIdx.x;
  if (i < E) {
    unsigned long long w = edges[i];
    int r = (int)(unsigned int)(w & 0xffffffffull);
    float ewv = __uint_as_float((unsigned int)(w >> 32));
    float nrm = dis[r] * ewv;
    edges[i] = ((unsigned long long)__float_as_uint(nrm) << 32) | (unsigned int)r;
  }
}

// ---------------------------------------------------------------- GEMM2 (row-major, LDS-staged)

static __global__ __launch_bounds__(256)
void gemm2_mfma(const unsigned short* __restrict__ A, const unsigned short* __restrict__ BT,
                unsigned short* __restrict__ C) {
  __shared__ unsigned short As[128 * 40];
  __shared__ unsigned short Bs[128 * 40];
  int t = threadIdx.x;
  int wv = t >> 6, lane = t & 63;
  int quad = lane >> 4, l15 = lane & 15;
  int m0 = blockIdx.x * 128;

  f32x4 acc[4][4];
#pragma unroll
  for (int i = 0; i < 4; ++i)
#pragma unroll
    for (int j = 0; j < 4; ++j) acc[i][j] = (f32x4){0.f, 0.f, 0.f, 0.f};

  int sr = t >> 1, sc = (t & 1) * 16;

  for (int k0 = 0; k0 < 128; k0 += 32) {
    short8 a0 = *(const short8*)(A + (size_t)(m0 + sr) * 128 + k0 + sc);
    short8 a1 = *(const short8*)(A + (size_t)(m0 + sr) * 128 + k0 + sc + 8);
    *(short8*)&As[sr * 40 + sc]     = a0;
    *(short8*)&As[sr * 40 + sc + 8] = a1;
    short8 b0 = *(const short8*)(BT + (size_t)sr * 128 + k0 + sc);
    short8 b1 = *(const short8*)(BT + (size_t)sr * 128 + k0 + sc + 8);
    *(short8*)&Bs[sr * 40 + sc]     = b0;
    *(short8*)&Bs[sr * 40 + sc + 8] = b1;
    __syncthreads();

    int mb = (wv >> 1) * 64, nb = (wv & 1) * 64;
    short8 af[4], bf[4];
#pragma unroll
    for (int mt = 0; mt < 4; ++mt)
      af[mt] = *(const short8*)&As[(mb + mt * 16 + l15) * 40 + quad * 8];
#pragma unroll
    for (int nt = 0; nt < 4; ++nt)
      bf[nt] = *(const short8*)&Bs[(nb + nt * 16 + l15) * 40 + quad * 8];
#pragma unroll
    for (int mt = 0; mt < 4; ++mt)
#pragma unroll
      for (int nt = 0; nt < 4; ++nt)
        acc[mt][nt] = __builtin_amdgcn_mfma_f32_16x16x32_bf16(af[mt], bf[nt], acc[mt][nt], 0, 0, 0);
    __syncthreads();
  }

  int mb = (wv >> 1) * 64, nb = (wv & 1) * 64;
#pragma unroll
  for (int mt = 0; mt < 4; ++mt)
#pragma unroll
    for (int nt = 0; nt < 4; ++nt) {
      int n = nb + nt * 16 + l15;
#pragma unroll
      for (int reg = 0; reg < 4; ++reg) {
        size_t m = (size_t)(m0 + mb + mt * 16 + quad * 4 + reg);
        C[m * 128 + n] = f2bf(acc[mt][nt][reg]);
      }
    }
}

// ---------------------------------------------------------------- propagation core (row-major)

#define PROP_GATHER_BODY                                                        \
  int c0 = lane * 2;                                                            \
  float d = dis[w];                                                             \
  float acc0, acc1;                                                             \
  {                                                                             \
    unsigned int u = Hsrc[(size_t)w * 64 + lane];                               \
    acc0 = d * __uint_as_float(u << 16);                                        \
    acc1 = d * __uint_as_float(u & 0xffff0000u);                                \
  }                                                                             \
  int s = start[w], n = cnt[w];                                                 \
  int k = 0;                                                                    \
  while (k < n) {                                                               \
    int chunk = min(n - k, 64);                                                 \
    int idx = 0;                                                                \
    float wt = 0.f;                                                             \
    if (lane < chunk) {                                                         \
      long long ev = (long long)edges[s + k + lane];                            \
      idx = (int)(unsigned int)(ev & 0xffffffffLL);                             \
      wt  = __int_as_float((int)(ev >> 32));                                    \
    }                                                                           \
    for (int j = 0; j < chunk; j += 8) {                                        \
      int   i0 = __shfl(idx, j + 0, 64), i1 = __shfl(idx, j + 1, 64);           \
      int   i2 = __shfl(idx, j + 2, 64), i3 = __shfl(idx, j + 3, 64);           \
      int   i4 = __shfl(idx, j + 4, 64), i5 = __shfl(idx, j + 5, 64);           \
      int   i6 = __shfl(idx, j + 6, 64), i7 = __shfl(idx, j + 7, 64);           \
      float w0 = __shfl(wt, j + 0, 64), w1 = __shfl(wt, j + 1, 64);             \
      float w2 = __shfl(wt, j + 2, 64), w3 = __shfl(wt, j + 3, 64);             \
      float w4 = __shfl(wt, j + 4, 64), w5 = __shfl(wt, j + 5, 64);             \
      float w6 = __shfl(wt, j + 6, 64), w7 = __shfl(wt, j + 7, 64);             \
      unsigned int u0 = Hsrc[(size_t)i0 * 64 + lane];                           \
      unsigned int u1 = Hsrc[(size_t)i1 * 64 + lane];                           \
      unsigned int u2 = Hsrc[(size_t)i2 * 64 + lane];                           \
      unsigned int u3 = Hsrc[(size_t)i3 * 64 + lane];                           \
      unsigned int u4 = Hsrc[(size_t)i4 * 64 + lane];                           \
      unsigned int u5 = Hsrc[(size_t)i5 * 64 + lane];                           \
      unsigned int u6 = Hsrc[(size_t)i6 * 64 + lane];                           \
      unsigned int u7 = Hsrc[(size_t)i7 * 64 + lane];                           \
      acc0 = fmaf(w0, __uint_as_float(u0 << 16), acc0);                         \
      acc1 = fmaf(w0, __uint_as_float(u0 & 0xffff0000u), acc1);                 \
      acc0 = fmaf(w1, __uint_as_float(u1 << 16), acc0);                         \
      acc1 = fmaf(w1, __uint_as_float(u1 & 0xffff0000u), acc1);                 \
      acc0 = fmaf(w2, __uint_as_float(u2 << 16), acc0);                         \
      acc1 = fmaf(w2, __uint_as_float(u2 & 0xffff0000u), acc1);                 \
      acc0 = fmaf(w3, __uint_as_float(u3 << 16), acc0);                         \
      acc1 = fmaf(w3, __uint_as_float(u3 & 0xffff0000u), acc1);                 \
      acc0 = fmaf(w4, __uint_as_float(u4 << 16), acc0);                         \
      acc1 = fmaf(w4, __uint_as_float(u4 & 0xffff0000u), acc1);                 \
      acc0 = fmaf(w5, __uint_as_float(u5 << 16), acc0);                         \
      acc1 = fmaf(w5, __uint_as_float(u5 & 0xffff0000u), acc1);                 \
      acc0 = fmaf(w6, __uint_as_float(u6 << 16), acc0);                         \
      acc1 = fmaf(w6, __uint_as_float(u6 & 0xffff0000u), acc1);                 \
      acc0 = fmaf(w7, __uint_as_float(u7 << 16), acc0);                         \
      acc1 = fmaf(w7, __uint_as_float(u7 & 0xffff0000u), acc1);                 \
    }                                                                           \
    k += chunk;                                                                 \
  }                                                                             \
  acc0 *= d;                                                                    \
  acc1 *= d;

static __global__ __launch_bounds__(256)
void prop128_bf16out(const unsigned int* __restrict__ Hsrc,
                     const int* __restrict__ start, const int* __restrict__ cnt,
                     const unsigned long long* __restrict__ edges,
                     const float* __restrict__ dis,
                     const float* __restrict__ bvec,
                     const float* __restrict__ g, const float* __restrict__ be,
                     const float* __restrict__ mean, const float* __restrict__ var,
                     unsigned int* __restrict__ Outb, int N) {
  int w = (int)((blockIdx.x * blockDim.x + threadIdx.x) >> 6);
  int lane = threadIdx.x & 63;
  if (w >= N) return;
  PROP_GATHER_BODY
  float x0 = acc0 + bvec[c0];
  float x1 = acc1 + bvec[c0 + 1];
  float s0 = g[c0] * rsqrtf(var[c0] + BN_EPS);
  float s1 = g[c0 + 1] * rsqrtf(var[c0 + 1] + BN_EPS);
  x0 = fmaxf((x0 - mean[c0]) * s0 + be[c0], 0.f);
  x1 = fmaxf((x1 - mean[c0 + 1]) * s1 + be[c0 + 1], 0.f);
  unsigned int packed = (unsigned int)f2bf(x0) | ((unsigned int)f2bf(x1) << 16);
  Outb[(size_t)w * 64 + lane] = packed;
}

static __global__ __launch_bounds__(256)
void prop128_w3out(const unsigned int* __restrict__ Hsrc,
                   const int* __restrict__ start, const int* __restrict__ cnt,
                   const unsigned long long* __restrict__ edges,
                   const float* __restrict__ dis,
                   const float* __restrict__ bvec,
                   const float* __restrict__ g, const float* __restrict__ be,
                   const float* __restrict__ mean, const float* __restrict__ var,
                   const unsigned int* __restrict__ resb, const float* __restrict__ W3,
                   float* __restrict__ h3, int N) {
  int w = (int)((blockIdx.x * blockDim.x + threadIdx.x) >> 6);
  int lane = threadIdx.x & 63;
  if (w >= N) return;
  PROP_GATHER_BODY
  unsigned int ru = resb[(size_t)w * 64 + lane];
  float x0 = acc0 + bvec[c0]     + __uint_as_float(ru << 16);
  float x1 = acc1 + bvec[c0 + 1] + __uint_as_float(ru & 0xffff0000u);
  float s0 = g[c0] * rsqrtf(var[c0] + BN_EPS);
  float s1 = g[c0 + 1] * rsqrtf(var[c0 + 1] + BN_EPS);
  x0 = fmaxf((x0 - mean[c0]) * s0 + be[c0], 0.f);
  x1 = fmaxf((x1 - mean[c0 + 1]) * s1 + be[c0 + 1], 0.f);
  float v = x0 * W3[c0] + x1 * W3[c0 + 1];
#pragma unroll
  for (int off = 32; off > 0; off >>= 1) v += __shfl_down(v, off, 64);
  if (lane == 0) h3[w] = v;
}

// ---------------------------------------------------------------- final 1-wide propagation

static __global__ __launch_bounds__(256)
void prop3_kernel(const float* __restrict__ h3,
                  const int* __restrict__ start, const int* __restrict__ cnt,
                  const unsigned long long* __restrict__ edges,
                  const float* __restrict__ dis, const float* __restrict__ b3,
                  float* __restrict__ out, int N) {
  int tid = blockIdx.x * blockDim.x + threadIdx.x;
  int i = tid >> 2;
  int sub = tid & 3;
  if (i >= N) return;
  float acc = 0.f;
  int s = start[i], n = cnt[i];
  for (int k = sub; k < n; k += 4) {
    unsigned long long ev = edges[s + k];
    int src = (int)(unsigned int)(ev & 0xffffffffull);
    float wt = __uint_as_float((unsigned int)(ev >> 32));
    acc = fmaf(wt, h3[src], acc);
  }
  acc += __shfl_xor(acc, 1, 64);
  acc += __shfl_xor(acc, 2, 64);
  if (sub == 0) {
    float d = dis[i];
    out[i] = (acc + d * h3[i]) * d + b3[0];
  }
}

// ---------------------------------------------------------------- launch

extern "C" void kernel_launch(void* const* d_in, const int* in_sizes, int n_in,
                              void* d_out, int out_size, void* d_ws, size_t ws_size,
                              hipStream_t stream) {
  const float* x    = (const float*)d_in[0];
  const int*   ei   = (const int*)d_in[1];
  const float* ew   = (const float*)d_in[2];
  const float* W1   = (const float*)d_in[3];
  const float* b1   = (const float*)d_in[4];
  const float* W2   = (const float*)d_in[5];
  const float* b2   = (const float*)d_in[6];
  const float* W3   = (const float*)d_in[7];
  const float* b3   = (const float*)d_in[8];
  const float* Wres = (const float*)d_in[9];
  const float* g1   = (const float*)d_in[10];
  const float* be1  = (const float*)d_in[11];
  const float* m1   = (const float*)d_in[12];
  const float* v1   = (const float*)d_in[13];
  const float* g2   = (const float*)d_in[14];
  const float* be2  = (const float*)d_in[15];
  const float* m2   = (const float*)d_in[16];
  const float* v2   = (const float*)d_in[17];

  int Hh = in_sizes[4];            // 128
  int V  = in_sizes[3] / Hh;       // 256
  int N  = in_sizes[0] / V;        // 100000
  int E  = in_sizes[2];            // 1600000
  const int* row = ei;
  const int* col = ei + E;

  int Mp = ((N + 127) / 128) * 128;
  int CB  = (E + EPB - 1) / EPB;   // chunk blocks (count/scatter)
  int NBK = (N + 127) >> 7;        // column buckets (128 cols each)

  char* p = (char*)d_ws;
  auto alloc = [&](size_t bytes) -> char* {
    char* r = p;
    p += (bytes + 255) & ~(size_t)255;
    return r;
  };
  int*   BBt    = (int*)alloc((size_t)CB * NBK * 4);   // TRANSPOSED counts -> cursor bases
  int*   total  = (int*)alloc((size_t)NBK * 4);
  int*   bucketBase = (int*)alloc((size_t)(NBK + 1) * 4);
  float* dis    = (float*)alloc((size_t)N * 4);
  int*   cnt    = (int*)  alloc((size_t)N * 4);
  int*   startA = (int*)  alloc((size_t)N * 4);
  unsigned long long* tmp   = (unsigned long long*)alloc((size_t)E * 8);
  unsigned long long* edges = (unsigned long long*)alloc((size_t)E * 8);
  float* h3     = (float*)alloc((size_t)N * 4);
  unsigned short* B2  = (unsigned short*)alloc((size_t)256 * 256 * 2);
  unsigned short* BT2 = (unsigned short*)alloc((size_t)128 * 128 * 2);
  unsigned short* bufG  = (unsigned short*)alloc((size_t)Mp * 128 * 2);  // h0, then h1W2 (bf16)
  unsigned short* bufH1 = (unsigned short*)alloc((size_t)Mp * 128 * 2);  // h1 bf16
  unsigned short* bufRes = (unsigned short*)alloc((size_t)Mp * 128 * 2); // x@Wres bf16
  (void)ws_size; (void)n_in; (void)out_size;

  int TB = 256;
  cast_weights<<<(256 * 256 + 128 * 128 + TB - 1) / TB, TB, 0, stream>>>(W1, Wres, W2, B2, BT2);

  // fused: bucket-count (blocks [0,CB)) + GEMM1 (blocks [CB,..))
  int gB = Mp / 64;
  fused_count_gemm1<<<CB + gB, TB, 0, stream>>>(x, B2, bufG, bufRes, N,
                                                col, BBt, E, CB, NBK);

  totals_kernel<<<NBK, 256, 0, stream>>>(BBt, total, CB, NBK);
  base_kernel<<<1, 256, 0, stream>>>(total, bucketBase, NBK);
  off_kernel<<<NBK, 256, 0, stream>>>(BBt, bucketBase, CB, NBK);
  scatter_kernel<<<CB, 256, 0, stream>>>(row, col, ew, BBt, tmp, E, CB, NBK);
  bucket_csr<<<NBK, 256, 0, stream>>>(tmp, bucketBase, cnt, startA, dis, edges, N);
  finalize_kernel<<<(E + 255) / 256, 256, 0, stream>>>(edges, dis, E);

  // prop1: h1 = relu(bn1(agg(h0) + b1)) -> bufH1 (bf16)
  int propBlocks = (int)(((size_t)N * 64 + TB - 1) / TB);
  prop128_bf16out<<<propBlocks, TB, 0, stream>>>((const unsigned int*)bufG, startA, cnt,
                                                 edges, dis, b1, g1, be1, m1, v1,
                                                 (unsigned int*)bufH1, N);

  // GEMM2: h1 @ W2 -> bufG (bf16, reused)
  gemm2_mfma<<<Mp / 128, 256, 0, stream>>>(bufH1, BT2, bufG);

  // prop2 + fused W3: h3 = relu(bn2(agg(h1W2) + b2 + res)) . W3
  prop128_w3out<<<propBlocks, TB, 0, stream>>>((const unsigned int*)bufG, startA, cnt,
                                               edges, dis, b2, g2, be2, m2, v2,
                                               (const unsigned int*)bufRes, W3, h3, N);

  // out = agg(h3) + b3 (4 lanes/node)
  prop3_kernel<<<(int)(((size_t)N * 4 + TB - 1) / TB), TB, 0, stream>>>(h3, startA, cnt,
                                                                        edges, dis, b3,
                                                                        (float*)d_out, N);
}